// Round 1
// baseline (640.934 us; speedup 1.0000x reference)
//
#include <hip/hip_runtime.h>
#include <cstdint>
#include <cstddef>

typedef __bf16 bf16;
typedef __bf16 bf16x4_t __attribute__((ext_vector_type(4)));
typedef __bf16 bf16x8_t __attribute__((ext_vector_type(8)));
typedef float f32x4_t __attribute__((ext_vector_type(4)));

#define DEV __device__ __forceinline__

static constexpr int CD  = 768;    // channels
static constexpr int C3  = 2304;   // 3*C
static constexpr int SEQ = 2048;
static constexpr int NB  = 4;      // batch
static constexpr int NH  = 12;     // heads
static constexpr int HDM = 64;     // head dim
static constexpr int BHN = NB * NH; // 48

DEV void async16(const void* g, void* l) {
  __builtin_amdgcn_global_load_lds(
      (const __attribute__((address_space(1))) void*)g,
      (__attribute__((address_space(3))) void*)l, 16, 0, 0);
}

DEV int swz(int r) { return (r ^ (r >> 2)) & 3; }

// ---------------- cast x fp32 -> bf16 ----------------
__global__ void k_cast(const float* __restrict__ x, bf16* __restrict__ o, int n4) {
  int i = blockIdx.x * blockDim.x + threadIdx.x;
  int stride = gridDim.x * blockDim.x;
  for (; i < n4; i += stride) {
    float4 v = reinterpret_cast<const float4*>(x)[i];
    bf16x4_t b;
    b[0] = (bf16)v.x; b[1] = (bf16)v.y; b[2] = (bf16)v.z; b[3] = (bf16)v.w;
    reinterpret_cast<bf16x4_t*>(o)[i] = b;
  }
}

// ---------------- weight folding (LoRA -> effective weights) ----------------
// W_qkv_eff[o][c] = W[o][c] + 2 * sum_r Bq[o][r] * Aq[r][c]
__global__ void k_prep_qkvw(const float* __restrict__ W, const float* __restrict__ Aq,
                            const float* __restrict__ Bq, bf16* __restrict__ We) {
  int idx = blockIdx.x * 256 + threadIdx.x;       // 2304*768
  int o = idx / CD, c = idx % CD;
  float s = 0.f;
#pragma unroll
  for (int r = 0; r < 8; ++r) s += Bq[o * 8 + r] * Aq[r * CD + c];
  We[idx] = (bf16)(W[idx] + 2.0f * s);
}

// T[r][c'] = sum_c Ap[r][c] * Wp[c][c']
__global__ void k_prep_T(const float* __restrict__ Ap, const float* __restrict__ Wp,
                         float* __restrict__ T) {
  int idx = blockIdx.x * 256 + threadIdx.x;       // 8*768
  int r = idx / CD, cp = idx % CD;
  float s = 0.f;
  for (int c = 0; c < CD; ++c) s += Ap[r * CD + c] * Wp[(size_t)c * CD + cp];
  T[idx] = s;
}

// W_p_eff[o][c'] = Wp[o][c'] + 2 * sum_r Bp[o][r] * T[r][c']
__global__ void k_prep_projw(const float* __restrict__ Wp, const float* __restrict__ Bp,
                             const float* __restrict__ T, bf16* __restrict__ We) {
  int idx = blockIdx.x * 256 + threadIdx.x;       // 768*768
  int o = idx / CD, cp = idx % CD;
  float s = 0.f;
#pragma unroll
  for (int r = 0; r < 8; ++r) s += Bp[o * 8 + r] * T[r * CD + cp];
  We[idx] = (bf16)(Wp[idx] + 2.0f * s);
}

// b_eff[o] = bp[o] + 2 * sum_r Bp[o][r] * (sum_c Ap[r][c] * bp[c])
__global__ void k_prep_beff(const float* __restrict__ bp, const float* __restrict__ Ap,
                            const float* __restrict__ Bp, float* __restrict__ be) {
  int o = blockIdx.x * 256 + threadIdx.x;
  if (o >= CD) return;
  float s = 0.f;
  for (int r = 0; r < 8; ++r) {
    float t = 0.f;
    for (int c = 0; c < CD; ++c) t += Ap[r * CD + c] * bp[c];
    s += Bp[o * 8 + r] * t;
  }
  be[o] = bp[o] + 2.0f * s;
}

// ---------------- main GEMM: C[m][n] = sum_k A[m][k]*B[n][k] ----------------
// 128x128 tile, BK=32, 4 waves (2x2), each wave 64x64 (4x4 frags of 16x16x32).
// global_load_lds(16B) staging, double-buffered LDS, XOR chunk swizzle (2-way max).
// MODE 0: A=xb, B=W_qkv_eff -> scatter to Q(scaled,+qbias)/K/V(+vbias) [BH][SEQ][64]
// MODE 1: A=attnout, B=W_p_eff -> d_out fp32 + b_eff
template <int MODE>
__global__ __launch_bounds__(256) void k_gemm(
    const bf16* __restrict__ Ag, const bf16* __restrict__ Bg,
    const float* __restrict__ qb, const float* __restrict__ vb,
    bf16* __restrict__ Qo, bf16* __restrict__ Ko, bf16* __restrict__ Vo,
    const float* __restrict__ beff, float* __restrict__ Fo) {
  __shared__ bf16 lds[2][2][128 * 32];
  const int tid = threadIdx.x;
  const int w = tid >> 6, lane = tid & 63;
  const int lr = lane & 15, lg = lane >> 4;
  const int m0 = blockIdx.y * 128, n0 = blockIdx.x * 128;
  const int wm = w >> 1, wn = w & 1;

  // staging map: issue i, thread tid covers LDS bytes i*4096 + tid*16
  const int r0 = tid >> 2, gp0 = tid & 3;
  const int r1 = 64 + r0;
  const bf16* gA0 = Ag + (size_t)(m0 + r0) * CD + (gp0 ^ swz(r0)) * 8;
  const bf16* gA1 = Ag + (size_t)(m0 + r1) * CD + (gp0 ^ swz(r1)) * 8;
  const bf16* gB0 = Bg + (size_t)(n0 + r0) * CD + (gp0 ^ swz(r0)) * 8;
  const bf16* gB1 = Bg + (size_t)(n0 + r1) * CD + (gp0 ^ swz(r1)) * 8;
  const int dd0 = w * 1024, dd1 = 4096 + w * 1024;

  f32x4_t acc[4][4] = {};

  auto stage = [&](int buf, int kof) {
    char* ba = (char*)&lds[buf][0][0];
    char* bb = (char*)&lds[buf][1][0];
    async16(gA0 + kof, ba + dd0);
    async16(gA1 + kof, ba + dd1);
    async16(gB0 + kof, bb + dd0);
    async16(gB1 + kof, bb + dd1);
  };

  stage(0, 0);
  int cur = 0;
  const int NK = CD / 32;
  for (int kt = 0; kt < NK; ++kt) {
    __syncthreads();  // drains vmcnt -> buf[cur] ready; joins readers of buf[cur^1]
    if (kt + 1 < NK) stage(cur ^ 1, (kt + 1) * 32);
    const char* ba = (const char*)&lds[cur][0][0];
    const char* bb = (const char*)&lds[cur][1][0];
    bf16x8_t af[4], bfr[4];
#pragma unroll
    for (int mi = 0; mi < 4; ++mi) {
      int rr = wm * 64 + mi * 16 + lr;
      af[mi] = *(const bf16x8_t*)(ba + rr * 64 + ((lg ^ swz(rr)) * 16));
    }
#pragma unroll
    for (int ni = 0; ni < 4; ++ni) {
      int rr = wn * 64 + ni * 16 + lr;
      bfr[ni] = *(const bf16x8_t*)(bb + rr * 64 + ((lg ^ swz(rr)) * 16));
    }
#pragma unroll
    for (int mi = 0; mi < 4; ++mi)
#pragma unroll
      for (int ni = 0; ni < 4; ++ni)
        acc[mi][ni] = __builtin_amdgcn_mfma_f32_16x16x32_bf16(af[mi], bfr[ni], acc[mi][ni], 0, 0, 0);
    cur ^= 1;
  }

  if (MODE == 0) {
    const int t = n0 / CD;  // block-uniform: 768 % 128 == 0
#pragma unroll
    for (int mi = 0; mi < 4; ++mi) {
#pragma unroll
      for (int ni = 0; ni < 4; ++ni) {
        const int n = n0 + wn * 64 + ni * 16 + lr;
        const int rem = n - t * CD;
        const int h = rem >> 6, hd = rem & 63;
#pragma unroll
        for (int j = 0; j < 4; ++j) {
          const int m = m0 + wm * 64 + mi * 16 + lg * 4 + j;
          const int b = m >> 11, nn = m & 2047;
          const size_t oa = ((size_t)((b * NH + h) * SEQ + nn)) * HDM + hd;
          float val = acc[mi][ni][j];
          if (t == 0)
            Qo[oa] = (bf16)((val + qb[rem]) * 0.125f);  // fold softmax scale (exact pow2)
          else if (t == 1)
            Ko[oa] = (bf16)val;
          else
            Vo[oa] = (bf16)(val + vb[rem]);
        }
      }
    }
  } else {
#pragma unroll
    for (int mi = 0; mi < 4; ++mi)
#pragma unroll
      for (int ni = 0; ni < 4; ++ni) {
        const int n = n0 + wn * 64 + ni * 16 + lr;
#pragma unroll
        for (int j = 0; j < 4; ++j) {
          const int m = m0 + wm * 64 + mi * 16 + lg * 4 + j;
          Fo[(size_t)m * CD + n] = acc[mi][ni][j] + beff[n];
        }
      }
  }
}

// ---------------- V transpose: [BH][SEQ][64] -> [BH][64][SEQ] ----------------
__global__ void k_trv(const bf16* __restrict__ V, bf16* __restrict__ Vt) {
  __shared__ bf16 t[64][72];  // +8 pad
  const int bh = blockIdx.y, s0 = blockIdx.x * 64;
  const int tid = threadIdx.x;
  const int row = tid >> 2, cc = (tid & 3) * 16;
  const bf16* src = V + ((size_t)bh * SEQ + s0 + row) * HDM + cc;
  bf16x8_t a = *(const bf16x8_t*)src;
  bf16x8_t b2 = *(const bf16x8_t*)(src + 8);
#pragma unroll
  for (int i = 0; i < 8; ++i) { t[row][cc + i] = a[i]; t[row][cc + 8 + i] = b2[i]; }
  __syncthreads();
  bf16x8_t o0, o1;
#pragma unroll
  for (int i = 0; i < 8; ++i) { o0[i] = t[cc + i][row]; o1[i] = t[cc + 8 + i][row]; }
  bf16* dst = Vt + ((size_t)bh * HDM + row) * SEQ + s0 + cc;
  *(bf16x8_t*)dst = o0;
  *(bf16x8_t*)(dst + 8) = o1;
}

// ---------------- flash attention ----------------
// block = 4 waves, 64 q-rows per block (16/wave). KV block = 64.
// Q pre-scaled. Online softmax in registers (wave-parallel, shfl over 16-lane groups).
// P staged per-wave in XOR-swizzled LDS for the PV A-operand.
__global__ __launch_bounds__(256) void k_attn(const bf16* __restrict__ Q,
                                              const bf16* __restrict__ Kg,
                                              const bf16* __restrict__ Vt,
                                              bf16* __restrict__ Ao) {
  __shared__ bf16 P[4][16 * 64];
  const int tid = threadIdx.x;
  const int w = tid >> 6, lane = tid & 63;
  const int lr = lane & 15, lg = lane >> 4;
  const int bh = blockIdx.y;
  const int b = bh / NH, h = bh % NH;
  const int qrow0 = blockIdx.x * 64 + w * 16;

  const bf16* Qp = Q + ((size_t)bh * SEQ + qrow0) * HDM;
  const bf16* Kp = Kg + (size_t)bh * SEQ * HDM;
  const bf16* Vp = Vt + (size_t)bh * HDM * SEQ;

  bf16x8_t qf0 = *(const bf16x8_t*)(Qp + lr * HDM + lg * 8);
  bf16x8_t qf1 = *(const bf16x8_t*)(Qp + lr * HDM + 32 + lg * 8);

  f32x4_t oacc[4] = {};
  float mrun[4] = {-1e30f, -1e30f, -1e30f, -1e30f};
  float lrun[4] = {0.f, 0.f, 0.f, 0.f};

  for (int kb = 0; kb < SEQ; kb += 64) {
    f32x4_t st[4];
#pragma unroll
    for (int nt = 0; nt < 4; ++nt) {
      const bf16* kp = Kp + (size_t)(kb + nt * 16 + lr) * HDM + lg * 8;
      bf16x8_t kf0 = *(const bf16x8_t*)kp;
      bf16x8_t kf1 = *(const bf16x8_t*)(kp + 32);
      f32x4_t z = {0.f, 0.f, 0.f, 0.f};
      z = __builtin_amdgcn_mfma_f32_16x16x32_bf16(qf0, kf0, z, 0, 0, 0);
      st[nt] = __builtin_amdgcn_mfma_f32_16x16x32_bf16(qf1, kf1, z, 0, 0, 0);
    }
    float rm[4], rs[4], corr[4];
#pragma unroll
    for (int j = 0; j < 4; ++j)
      rm[j] = fmaxf(fmaxf(st[0][j], st[1][j]), fmaxf(st[2][j], st[3][j]));
#pragma unroll
    for (int d = 1; d < 16; d <<= 1)
#pragma unroll
      for (int j = 0; j < 4; ++j) rm[j] = fmaxf(rm[j], __shfl_xor(rm[j], d, 64));
#pragma unroll
    for (int j = 0; j < 4; ++j) {
      float mn = fmaxf(mrun[j], rm[j]);
      corr[j] = __expf(mrun[j] - mn);
      mrun[j] = mn;
      rs[j] = 0.f;
    }
#pragma unroll
    for (int nt = 0; nt < 4; ++nt)
#pragma unroll
      for (int j = 0; j < 4; ++j) {
        float p = __expf(st[nt][j] - mrun[j]);
        st[nt][j] = p;
        rs[j] += p;
      }
#pragma unroll
    for (int d = 1; d < 16; d <<= 1)
#pragma unroll
      for (int j = 0; j < 4; ++j) rs[j] += __shfl_xor(rs[j], d, 64);
#pragma unroll
    for (int j = 0; j < 4; ++j) lrun[j] = lrun[j] * corr[j] + rs[j];
#pragma unroll
    for (int dt = 0; dt < 4; ++dt)
#pragma unroll
      for (int j = 0; j < 4; ++j) oacc[dt][j] *= corr[j];
    // write P (bf16) to per-wave swizzled LDS: row = lg*4+j, col = nt*16+lr
#pragma unroll
    for (int nt = 0; nt < 4; ++nt)
#pragma unroll
      for (int j = 0; j < 4; ++j) {
        int row = lg * 4 + j, col = nt * 16 + lr;
        int c = (col >> 3) ^ (row & 7);
        P[w][row * 64 + c * 8 + (col & 7)] = (bf16)st[nt][j];
      }
    // PV: A = P rows (lane lr), B = Vt rows (16B contiguous)
#pragma unroll
    for (int mt = 0; mt < 2; ++mt) {
      int c = (mt * 4 + lg) ^ (lr & 7);
      bf16x8_t pf = *(const bf16x8_t*)&P[w][lr * 64 + c * 8];
#pragma unroll
      for (int dt = 0; dt < 4; ++dt) {
        const bf16* vp = Vp + (size_t)(dt * 16 + lr) * SEQ + kb + mt * 32 + lg * 8;
        bf16x8_t vf = *(const bf16x8_t*)vp;
        oacc[dt] = __builtin_amdgcn_mfma_f32_16x16x32_bf16(pf, vf, oacc[dt], 0, 0, 0);
      }
    }
  }
  // epilogue: attnout[b*SEQ + q][h*64 + d]
  bf16* dst = Ao + ((size_t)b * SEQ + qrow0) * CD + h * HDM;
#pragma unroll
  for (int dt = 0; dt < 4; ++dt)
#pragma unroll
    for (int j = 0; j < 4; ++j) {
      float v = oacc[dt][j] / lrun[j];
      dst[(size_t)(lg * 4 + j) * CD + dt * 16 + lr] = (bf16)v;
    }
}

// ---------------- launch ----------------
extern "C" void kernel_launch(void* const* d_in, const int* in_sizes, int n_in,
                              void* d_out, int out_size, void* d_ws, size_t ws_size,
                              hipStream_t stream) {
  const float* x    = (const float*)d_in[0];
  const float* qkvw = (const float*)d_in[1];
  const float* qb   = (const float*)d_in[2];
  const float* vb   = (const float*)d_in[3];
  const float* Aq   = (const float*)d_in[4];
  const float* Bq   = (const float*)d_in[5];
  const float* Wp   = (const float*)d_in[6];
  const float* bp   = (const float*)d_in[7];
  const float* Ap   = (const float*)d_in[8];
  const float* Bp   = (const float*)d_in[9];
  float* out = (float*)d_out;

  char* ws = (char*)d_ws;
  size_t off = 0;
  auto alloc = [&](size_t bytes) {
    void* p = ws + off;
    off += (bytes + 511) & ~size_t(511);
    return p;
  };
  const size_t M = (size_t)NB * SEQ;                 // 8192
  bf16* xb   = (bf16*)alloc(M * CD * 2);
  bf16* Wqe  = (bf16*)alloc((size_t)C3 * CD * 2);
  bf16* Wpe  = (bf16*)alloc((size_t)CD * CD * 2);
  float* T   = (float*)alloc(8 * CD * 4);
  float* be  = (float*)alloc(CD * 4);
  bf16* Qb   = (bf16*)alloc((size_t)BHN * SEQ * HDM * 2);
  bf16* Kb   = (bf16*)alloc((size_t)BHN * SEQ * HDM * 2);
  bf16* Vb   = (bf16*)alloc((size_t)BHN * SEQ * HDM * 2);
  bf16* Vtb  = (bf16*)alloc((size_t)BHN * SEQ * HDM * 2);
  bf16* attn = xb;  // xb is dead after gemm<0>; safe alias

  k_cast<<<2048, 256, 0, stream>>>(x, xb, (int)(M * CD / 4));
  k_prep_qkvw<<<(C3 * CD) / 256, 256, 0, stream>>>(qkvw, Aq, Bq, Wqe);
  k_prep_T<<<(8 * CD) / 256, 256, 0, stream>>>(Ap, Wp, T);
  k_prep_projw<<<(CD * CD) / 256, 256, 0, stream>>>(Wp, Bp, T, Wpe);
  k_prep_beff<<<3, 256, 0, stream>>>(bp, Ap, Bp, be);

  k_gemm<0><<<dim3(C3 / 128, M / 128), 256, 0, stream>>>(
      xb, Wqe, qb, vb, Qb, Kb, Vb, nullptr, nullptr);
  k_trv<<<dim3(SEQ / 64, BHN), 256, 0, stream>>>(Vb, Vtb);
  k_attn<<<dim3(SEQ / 64, BHN), 256, 0, stream>>>(Qb, Kb, Vtb, attn);
  k_gemm<1><<<dim3(CD / 128, M / 128), 256, 0, stream>>>(
      attn, Wpe, nullptr, nullptr, nullptr, nullptr, nullptr, be, out);
}

// Round 5
// 584.423 us; speedup vs baseline: 1.0967x; 1.0967x over previous
//
#include <hip/hip_runtime.h>
#include <cstdint>
#include <cstddef>

typedef __bf16 bf16;
typedef __bf16 bf16x4_t __attribute__((ext_vector_type(4)));
typedef __bf16 bf16x8_t __attribute__((ext_vector_type(8)));
typedef float f32x4_t __attribute__((ext_vector_type(4)));
typedef unsigned int u32;

#define DEV __device__ __forceinline__

static constexpr int CD  = 768;    // channels
static constexpr int C3  = 2304;   // 3*C
static constexpr int SEQ = 2048;
static constexpr int NB  = 4;      // batch
static constexpr int NH  = 12;     // heads
static constexpr int HDM = 64;     // head dim
static constexpr int BHN = NB * NH; // 48
static constexpr float QSCALE = 0.125f;  // exact pow2

DEV void async16(const void* g, void* l) {
  __builtin_amdgcn_global_load_lds(
      (const __attribute__((address_space(1))) void*)g,
      (__attribute__((address_space(3))) void*)l, 16, 0, 0);
}

DEV int swz(int r) { return (r ^ (r >> 2)) & 3; }

// pack two fp32 -> one u32 of 2 bf16 via compiler (bf16) casts (RTNE)
DEV u32 pack_bf16(float lo, float hi) {
  unsigned short l = __builtin_bit_cast(unsigned short, (bf16)lo);
  unsigned short h = __builtin_bit_cast(unsigned short, (bf16)hi);
  return ((u32)h << 16) | (u32)l;
}

// ---------------- cast x fp32 -> bf16 ----------------
__global__ void k_cast(const float* __restrict__ x, bf16* __restrict__ o, int n4) {
  int i = blockIdx.x * blockDim.x + threadIdx.x;
  int stride = gridDim.x * blockDim.x;
  for (; i < n4; i += stride) {
    float4 v = reinterpret_cast<const float4*>(x)[i];
    bf16x4_t b;
    b[0] = (bf16)v.x; b[1] = (bf16)v.y; b[2] = (bf16)v.z; b[3] = (bf16)v.w;
    reinterpret_cast<bf16x4_t*>(o)[i] = b;
  }
}

// ---------------- weight folding (LoRA -> effective weights) ----------------
__global__ void k_prep_qkvw(const float* __restrict__ W, const float* __restrict__ Aq,
                            const float* __restrict__ Bq, bf16* __restrict__ We) {
  int idx = blockIdx.x * 256 + threadIdx.x;       // 2304*768
  int o = idx / CD, c = idx % CD;
  float s = 0.f;
#pragma unroll
  for (int r = 0; r < 8; ++r) s += Bq[o * 8 + r] * Aq[r * CD + c];
  We[idx] = (bf16)(W[idx] + 2.0f * s);
}

__global__ void k_prep_T(const float* __restrict__ Ap, const float* __restrict__ Wp,
                         float* __restrict__ T) {
  int idx = blockIdx.x * 256 + threadIdx.x;       // 8*768
  int r = idx / CD, cp = idx % CD;
  float s = 0.f;
  for (int c = 0; c < CD; ++c) s += Ap[r * CD + c] * Wp[(size_t)c * CD + cp];
  T[idx] = s;
}

__global__ void k_prep_projw(const float* __restrict__ Wp, const float* __restrict__ Bp,
                             const float* __restrict__ T, bf16* __restrict__ We) {
  int idx = blockIdx.x * 256 + threadIdx.x;       // 768*768
  int o = idx / CD, cp = idx % CD;
  float s = 0.f;
#pragma unroll
  for (int r = 0; r < 8; ++r) s += Bp[o * 8 + r] * T[r * CD + cp];
  We[idx] = (bf16)(Wp[idx] + 2.0f * s);
}

__global__ void k_prep_beff(const float* __restrict__ bp, const float* __restrict__ Ap,
                            const float* __restrict__ Bp, float* __restrict__ be) {
  int o = blockIdx.x * 256 + threadIdx.x;
  if (o >= CD) return;
  float s = 0.f;
  for (int r = 0; r < 8; ++r) {
    float t = 0.f;
    for (int c = 0; c < CD; ++c) t += Ap[r * CD + c] * bp[c];
    s += Bp[o * 8 + r] * t;
  }
  be[o] = bp[o] + 2.0f * s;
}

// ---------------- main GEMM: C[m][n] = sum_k A[m][k]*B[n][k] ----------------
template <int MODE>
__global__ __launch_bounds__(256) void k_gemm(
    const bf16* __restrict__ Ag, const bf16* __restrict__ Bg,
    const float* __restrict__ qb, const float* __restrict__ vb,
    bf16* __restrict__ Qo, bf16* __restrict__ Ko, bf16* __restrict__ Vo,
    const float* __restrict__ beff, float* __restrict__ Fo) {
  __shared__ bf16 lds[2][2][128 * 32];
  const int tid = threadIdx.x;
  const int w = tid >> 6, lane = tid & 63;
  const int lr = lane & 15, lg = lane >> 4;
  const int m0 = blockIdx.y * 128, n0 = blockIdx.x * 128;
  const int wm = w >> 1, wn = w & 1;

  const int r0 = tid >> 2, gp0 = tid & 3;
  const int r1 = 64 + r0;
  const bf16* gA0 = Ag + (size_t)(m0 + r0) * CD + (gp0 ^ swz(r0)) * 8;
  const bf16* gA1 = Ag + (size_t)(m0 + r1) * CD + (gp0 ^ swz(r1)) * 8;
  const bf16* gB0 = Bg + (size_t)(n0 + r0) * CD + (gp0 ^ swz(r0)) * 8;
  const bf16* gB1 = Bg + (size_t)(n0 + r1) * CD + (gp0 ^ swz(r1)) * 8;
  const int dd0 = w * 1024, dd1 = 4096 + w * 1024;

  f32x4_t acc[4][4] = {};

  auto stage = [&](int buf, int kof) {
    char* ba = (char*)&lds[buf][0][0];
    char* bb = (char*)&lds[buf][1][0];
    async16(gA0 + kof, ba + dd0);
    async16(gA1 + kof, ba + dd1);
    async16(gB0 + kof, bb + dd0);
    async16(gB1 + kof, bb + dd1);
  };

  stage(0, 0);
  int cur = 0;
  const int NK = CD / 32;
  for (int kt = 0; kt < NK; ++kt) {
    __syncthreads();
    if (kt + 1 < NK) stage(cur ^ 1, (kt + 1) * 32);
    const char* ba = (const char*)&lds[cur][0][0];
    const char* bb = (const char*)&lds[cur][1][0];
    bf16x8_t af[4], bfr[4];
#pragma unroll
    for (int mi = 0; mi < 4; ++mi) {
      int rr = wm * 64 + mi * 16 + lr;
      af[mi] = *(const bf16x8_t*)(ba + rr * 64 + ((lg ^ swz(rr)) * 16));
    }
#pragma unroll
    for (int ni = 0; ni < 4; ++ni) {
      int rr = wn * 64 + ni * 16 + lr;
      bfr[ni] = *(const bf16x8_t*)(bb + rr * 64 + ((lg ^ swz(rr)) * 16));
    }
#pragma unroll
    for (int mi = 0; mi < 4; ++mi)
#pragma unroll
      for (int ni = 0; ni < 4; ++ni)
        acc[mi][ni] = __builtin_amdgcn_mfma_f32_16x16x32_bf16(af[mi], bfr[ni], acc[mi][ni], 0, 0, 0);
    cur ^= 1;
  }

  if (MODE == 0) {
    const int t = n0 / CD;
#pragma unroll
    for (int mi = 0; mi < 4; ++mi) {
#pragma unroll
      for (int ni = 0; ni < 4; ++ni) {
        const int n = n0 + wn * 64 + ni * 16 + lr;
        const int rem = n - t * CD;
        const int h = rem >> 6, hd = rem & 63;
#pragma unroll
        for (int j = 0; j < 4; ++j) {
          const int m = m0 + wm * 64 + mi * 16 + lg * 4 + j;
          const int b = m >> 11, nn = m & 2047;
          const size_t oa = ((size_t)((b * NH + h) * SEQ + nn)) * HDM + hd;
          float val = acc[mi][ni][j];
          if (t == 0)
            Qo[oa] = (bf16)((val + qb[rem]) * QSCALE);
          else if (t == 1)
            Ko[oa] = (bf16)val;
          else
            Vo[oa] = (bf16)(val + vb[rem]);
        }
      }
    }
  } else {
#pragma unroll
    for (int mi = 0; mi < 4; ++mi)
#pragma unroll
      for (int ni = 0; ni < 4; ++ni) {
        const int n = n0 + wn * 64 + ni * 16 + lr;
#pragma unroll
        for (int j = 0; j < 4; ++j) {
          const int m = m0 + wm * 64 + mi * 16 + lg * 4 + j;
          Fo[(size_t)m * CD + n] = acc[mi][ni][j] + beff[n];
        }
      }
  }
}

// ---------------- V transpose: [BH][SEQ][64] -> [BH][64][SEQ] ----------------
__global__ void k_trv(const bf16* __restrict__ V, bf16* __restrict__ Vt) {
  __shared__ bf16 t[64][72];
  const int bh = blockIdx.y, s0 = blockIdx.x * 64;
  const int tid = threadIdx.x;
  const int row = tid >> 2, cc = (tid & 3) * 16;
  const bf16* src = V + ((size_t)bh * SEQ + s0 + row) * HDM + cc;
  bf16x8_t a = *(const bf16x8_t*)src;
  bf16x8_t b2 = *(const bf16x8_t*)(src + 8);
#pragma unroll
  for (int i = 0; i < 8; ++i) { t[row][cc + i] = a[i]; t[row][cc + 8 + i] = b2[i]; }
  __syncthreads();
  bf16x8_t o0, o1;
#pragma unroll
  for (int i = 0; i < 8; ++i) { o0[i] = t[cc + i][row]; o1[i] = t[cc + 8 + i][row]; }
  bf16* dst = Vt + ((size_t)bh * HDM + row) * SEQ + s0 + cc;
  *(bf16x8_t*)dst = o0;
  *(bf16x8_t*)(dst + 8) = o1;
}

// ---------------- flash attention (q-consistent swapped form) ----------------
// 4 waves/block, 16 q-rows/wave. KVBLK=64.
// QK^T swapped: st[nt] = mfma(K,Q) -> S^T; lane (lq,lg) reg j holds
// S[q=lq][k = nt*16 + lg*4 + j]. Softmax state (m,l,corr) per lane for q=lq:
// in-lane reduce + shfl_xor(16,32) over lg.
// P staged per-wave in LDS [16 q][72] at absolute k positions; PV reads P and
// Vt with the SAME (lg,j)->k map (layout-error cancels by construction).
// PV = mfma(V^T, P): O^T[d][q], col q = lq -> matches softmax state per lane.
__global__ __launch_bounds__(256) void k_attn(const bf16* __restrict__ Q,
                                              const bf16* __restrict__ Kg,
                                              const bf16* __restrict__ Vt,
                                              bf16* __restrict__ Ao) {
  __shared__ bf16 P[4][16 * 72];
  const int tid = threadIdx.x;
  const int w = tid >> 6, lane = tid & 63;
  const int lq = lane & 15, lg = lane >> 4;
  const int bh = blockIdx.y;
  const int b = bh / NH, h = bh % NH;
  const int qrow0 = blockIdx.x * 64 + w * 16;

  const bf16* Qp = Q + ((size_t)bh * SEQ + qrow0) * HDM;
  const bf16* Kp = Kg + (size_t)bh * SEQ * HDM;
  const bf16* Vp = Vt + (size_t)bh * HDM * SEQ;

  // Q as B-operand: col q = lq, d = lg*8 + jj (+32 for second half)
  bf16x8_t qf0 = *(const bf16x8_t*)(Qp + lq * HDM + lg * 8);
  bf16x8_t qf1 = *(const bf16x8_t*)(Qp + lq * HDM + 32 + lg * 8);

  f32x4_t oacc[4] = {};   // O^T: d = dt*16 + lg*4 + j, q = lq
  float mrun = -1e30f, lrun = 0.f;
  bf16* Pl = &P[w][0];

  for (int kb = 0; kb < SEQ; kb += 64) {
    // S^T tiles: A = K rows (k), B = Q cols (q)
    f32x4_t st[4];
#pragma unroll
    for (int nt = 0; nt < 4; ++nt) {
      const bf16* kp = Kp + (size_t)(kb + nt * 16 + lq) * HDM + lg * 8;
      bf16x8_t kf0 = *(const bf16x8_t*)kp;
      bf16x8_t kf1 = *(const bf16x8_t*)(kp + 32);
      f32x4_t z = {0.f, 0.f, 0.f, 0.f};
      z = __builtin_amdgcn_mfma_f32_16x16x32_bf16(kf0, qf0, z, 0, 0, 0);
      st[nt] = __builtin_amdgcn_mfma_f32_16x16x32_bf16(kf1, qf1, z, 0, 0, 0);
    }

    // online softmax for q=lq; lane holds k = nt*16 + lg*4 + j
    float m = st[0][0];
#pragma unroll
    for (int nt = 0; nt < 4; ++nt)
#pragma unroll
      for (int j = 0; j < 4; ++j) m = fmaxf(m, st[nt][j]);
    m = fmaxf(m, __shfl_xor(m, 16));
    m = fmaxf(m, __shfl_xor(m, 32));
    const float mnew = fmaxf(mrun, m);
    const float corr = __expf(mrun - mnew);
    mrun = mnew;
    float sum = 0.f;
#pragma unroll
    for (int nt = 0; nt < 4; ++nt)
#pragma unroll
      for (int j = 0; j < 4; ++j) {
        float p = __expf(st[nt][j] - mnew);
        st[nt][j] = p;
        sum += p;
      }
    sum += __shfl_xor(sum, 16);
    sum += __shfl_xor(sum, 32);
    lrun = lrun * corr + sum;
    // rescale O^T: col q = lq matches per-lane corr  (THE round-4 fix)
#pragma unroll
    for (int dt = 0; dt < 4; ++dt)
#pragma unroll
      for (int j = 0; j < 4; ++j) oacc[dt][j] *= corr;

    // stage P at absolute k: row q = lq, col k = nt*16 + lg*4 + {0,1}/{2,3}
#pragma unroll
    for (int nt = 0; nt < 4; ++nt) {
      *(u32*)(Pl + lq * 72 + nt * 16 + lg * 4)     = pack_bf16(st[nt][0], st[nt][1]);
      *(u32*)(Pl + lq * 72 + nt * 16 + lg * 4 + 2) = pack_bf16(st[nt][2], st[nt][3]);
    }

    // PV: A = Vt rows (d = dt*16+lq), B = P rows (q = lq); same (lg,j)->k map
#pragma unroll
    for (int mt = 0; mt < 2; ++mt) {
      bf16x8_t pf = *(const bf16x8_t*)(Pl + lq * 72 + mt * 32 + lg * 8);
#pragma unroll
      for (int dt = 0; dt < 4; ++dt) {
        const bf16* vp = Vp + (size_t)(dt * 16 + lq) * SEQ + kb + mt * 32 + lg * 8;
        bf16x8_t vf = *(const bf16x8_t*)vp;
        oacc[dt] = __builtin_amdgcn_mfma_f32_16x16x32_bf16(vf, pf, oacc[dt], 0, 0, 0);
      }
    }
  }

  // epilogue: lane (lq,lg) holds O[q=lq][d = dt*16 + lg*4 + j]
  const float inv = 1.0f / lrun;
  bf16* dst = Ao + ((size_t)b * SEQ + qrow0 + lq) * CD + h * HDM;
#pragma unroll
  for (int dt = 0; dt < 4; ++dt) {
    bf16x4_t o4;
#pragma unroll
    for (int j = 0; j < 4; ++j) o4[j] = (bf16)(oacc[dt][j] * inv);
    *(bf16x4_t*)(dst + dt * 16 + lg * 4) = o4;
  }
}

// ---------------- launch ----------------
extern "C" void kernel_launch(void* const* d_in, const int* in_sizes, int n_in,
                              void* d_out, int out_size, void* d_ws, size_t ws_size,
                              hipStream_t stream) {
  const float* x    = (const float*)d_in[0];
  const float* qkvw = (const float*)d_in[1];
  const float* qb   = (const float*)d_in[2];
  const float* vb   = (const float*)d_in[3];
  const float* Aq   = (const float*)d_in[4];
  const float* Bq   = (const float*)d_in[5];
  const float* Wp   = (const float*)d_in[6];
  const float* bp   = (const float*)d_in[7];
  const float* Ap   = (const float*)d_in[8];
  const float* Bp   = (const float*)d_in[9];
  float* out = (float*)d_out;

  char* ws = (char*)d_ws;
  size_t off = 0;
  auto alloc = [&](size_t bytes) {
    void* p = ws + off;
    off += (bytes + 511) & ~size_t(511);
    return p;
  };
  const size_t M = (size_t)NB * SEQ;                 // 8192
  bf16* xb   = (bf16*)alloc(M * CD * 2);
  bf16* Wqe  = (bf16*)alloc((size_t)C3 * CD * 2);
  bf16* Wpe  = (bf16*)alloc((size_t)CD * CD * 2);
  float* T   = (float*)alloc(8 * CD * 4);
  float* be  = (float*)alloc(CD * 4);
  bf16* Qb   = (bf16*)alloc((size_t)BHN * SEQ * HDM * 2);
  bf16* Kb   = (bf16*)alloc((size_t)BHN * SEQ * HDM * 2);
  bf16* Vb   = (bf16*)alloc((size_t)BHN * SEQ * HDM * 2);
  bf16* Vtb  = (bf16*)alloc((size_t)BHN * SEQ * HDM * 2);
  bf16* attn = xb;  // xb dead after gemm<0>

  k_cast<<<2048, 256, 0, stream>>>(x, xb, (int)(M * CD / 4));
  k_prep_qkvw<<<(C3 * CD) / 256, 256, 0, stream>>>(qkvw, Aq, Bq, Wqe);
  k_prep_T<<<(8 * CD) / 256, 256, 0, stream>>>(Ap, Wp, T);
  k_prep_projw<<<(CD * CD) / 256, 256, 0, stream>>>(Wp, Bp, T, Wpe);
  k_prep_beff<<<3, 256, 0, stream>>>(bp, Ap, Bp, be);

  k_gemm<0><<<dim3(C3 / 128, M / 128), 256, 0, stream>>>(
      xb, Wqe, qb, vb, Qb, Kb, Vb, nullptr, nullptr);
  k_trv<<<dim3(SEQ / 64, BHN), 256, 0, stream>>>(Vb, Vtb);
  k_attn<<<dim3(SEQ / 64, BHN), 256, 0, stream>>>(Qb, Kb, Vtb, attn);
  k_gemm<1><<<dim3(CD / 128, M / 128), 256, 0, stream>>>(
      attn, Wpe, nullptr, nullptr, nullptr, nullptr, nullptr, be, out);
}

// Round 6
// 359.577 us; speedup vs baseline: 1.7825x; 1.6253x over previous
//
#include <hip/hip_runtime.h>
#include <cstdint>
#include <cstddef>

typedef __bf16 bf16;
typedef __bf16 bf16x4_t __attribute__((ext_vector_type(4)));
typedef __bf16 bf16x8_t __attribute__((ext_vector_type(8)));
typedef float f32x4_t __attribute__((ext_vector_type(4)));
typedef unsigned int u32;
typedef u32 u32x2_t __attribute__((ext_vector_type(2)));

#define DEV __device__ __forceinline__

static constexpr int CD  = 768;    // channels
static constexpr int C3  = 2304;   // 3*C
static constexpr int SEQ = 2048;
static constexpr int NB  = 4;      // batch
static constexpr int NH  = 12;     // heads
static constexpr int HDM = 64;     // head dim
static constexpr int BHN = NB * NH; // 48
static constexpr float QSCALE = 0.125f;  // exact pow2

DEV void async16(const void* g, void* l) {
  __builtin_amdgcn_global_load_lds(
      (const __attribute__((address_space(1))) void*)g,
      (__attribute__((address_space(3))) void*)l, 16, 0, 0);
}

DEV int swz(int r) { return (r ^ (r >> 2)) & 3; }

// pack two fp32 -> one u32 of 2 bf16 via compiler (bf16) casts (RTNE)
DEV u32 pack_bf16(float lo, float hi) {
  unsigned short l = __builtin_bit_cast(unsigned short, (bf16)lo);
  unsigned short h = __builtin_bit_cast(unsigned short, (bf16)hi);
  return ((u32)h << 16) | (u32)l;
}

// ---------------- cast x fp32 -> bf16 ----------------
__global__ void k_cast(const float* __restrict__ x, bf16* __restrict__ o, int n4) {
  int i = blockIdx.x * blockDim.x + threadIdx.x;
  int stride = gridDim.x * blockDim.x;
  for (; i < n4; i += stride) {
    float4 v = reinterpret_cast<const float4*>(x)[i];
    bf16x4_t b;
    b[0] = (bf16)v.x; b[1] = (bf16)v.y; b[2] = (bf16)v.z; b[3] = (bf16)v.w;
    reinterpret_cast<bf16x4_t*>(o)[i] = b;
  }
}

// ---------------- weight folding (LoRA -> effective weights) ----------------
__global__ void k_prep_qkvw(const float* __restrict__ W, const float* __restrict__ Aq,
                            const float* __restrict__ Bq, bf16* __restrict__ We) {
  int idx = blockIdx.x * 256 + threadIdx.x;       // 2304*768
  int o = idx / CD, c = idx % CD;
  float s = 0.f;
#pragma unroll
  for (int r = 0; r < 8; ++r) s += Bq[o * 8 + r] * Aq[r * CD + c];
  We[idx] = (bf16)(W[idx] + 2.0f * s);
}

__global__ void k_prep_T(const float* __restrict__ Ap, const float* __restrict__ Wp,
                         float* __restrict__ T) {
  int idx = blockIdx.x * 256 + threadIdx.x;       // 8*768
  int r = idx / CD, cp = idx % CD;
  float s = 0.f;
  for (int c = 0; c < CD; ++c) s += Ap[r * CD + c] * Wp[(size_t)c * CD + cp];
  T[idx] = s;
}

__global__ void k_prep_projw(const float* __restrict__ Wp, const float* __restrict__ Bp,
                             const float* __restrict__ T, bf16* __restrict__ We) {
  int idx = blockIdx.x * 256 + threadIdx.x;       // 768*768
  int o = idx / CD, cp = idx % CD;
  float s = 0.f;
#pragma unroll
  for (int r = 0; r < 8; ++r) s += Bp[o * 8 + r] * T[r * CD + cp];
  We[idx] = (bf16)(Wp[idx] + 2.0f * s);
}

__global__ void k_prep_beff(const float* __restrict__ bp, const float* __restrict__ Ap,
                            const float* __restrict__ Bp, float* __restrict__ be) {
  int o = blockIdx.x * 256 + threadIdx.x;
  if (o >= CD) return;
  float s = 0.f;
  for (int r = 0; r < 8; ++r) {
    float t = 0.f;
    for (int c = 0; c < CD; ++c) t += Ap[r * CD + c] * bp[c];
    s += Bp[o * 8 + r] * t;
  }
  be[o] = bp[o] + 2.0f * s;
}

// ---------------- main GEMM: C[m][n] = sum_k A[m][k]*B[n][k] ----------------
template <int MODE>
__global__ __launch_bounds__(256) void k_gemm(
    const bf16* __restrict__ Ag, const bf16* __restrict__ Bg,
    const float* __restrict__ qb, const float* __restrict__ vb,
    bf16* __restrict__ Qo, bf16* __restrict__ Ko, bf16* __restrict__ Vo,
    const float* __restrict__ beff, float* __restrict__ Fo) {
  __shared__ bf16 lds[2][2][128 * 32];
  const int tid = threadIdx.x;
  const int w = tid >> 6, lane = tid & 63;
  const int lr = lane & 15, lg = lane >> 4;
  const int m0 = blockIdx.y * 128, n0 = blockIdx.x * 128;
  const int wm = w >> 1, wn = w & 1;

  const int r0 = tid >> 2, gp0 = tid & 3;
  const int r1 = 64 + r0;
  const bf16* gA0 = Ag + (size_t)(m0 + r0) * CD + (gp0 ^ swz(r0)) * 8;
  const bf16* gA1 = Ag + (size_t)(m0 + r1) * CD + (gp0 ^ swz(r1)) * 8;
  const bf16* gB0 = Bg + (size_t)(n0 + r0) * CD + (gp0 ^ swz(r0)) * 8;
  const bf16* gB1 = Bg + (size_t)(n0 + r1) * CD + (gp0 ^ swz(r1)) * 8;
  const int dd0 = w * 1024, dd1 = 4096 + w * 1024;

  f32x4_t acc[4][4] = {};

  auto stage = [&](int buf, int kof) {
    char* ba = (char*)&lds[buf][0][0];
    char* bb = (char*)&lds[buf][1][0];
    async16(gA0 + kof, ba + dd0);
    async16(gA1 + kof, ba + dd1);
    async16(gB0 + kof, bb + dd0);
    async16(gB1 + kof, bb + dd1);
  };

  stage(0, 0);
  int cur = 0;
  const int NK = CD / 32;
  for (int kt = 0; kt < NK; ++kt) {
    __syncthreads();
    if (kt + 1 < NK) stage(cur ^ 1, (kt + 1) * 32);
    const char* ba = (const char*)&lds[cur][0][0];
    const char* bb = (const char*)&lds[cur][1][0];
    bf16x8_t af[4], bfr[4];
#pragma unroll
    for (int mi = 0; mi < 4; ++mi) {
      int rr = wm * 64 + mi * 16 + lr;
      af[mi] = *(const bf16x8_t*)(ba + rr * 64 + ((lg ^ swz(rr)) * 16));
    }
#pragma unroll
    for (int ni = 0; ni < 4; ++ni) {
      int rr = wn * 64 + ni * 16 + lr;
      bfr[ni] = *(const bf16x8_t*)(bb + rr * 64 + ((lg ^ swz(rr)) * 16));
    }
#pragma unroll
    for (int mi = 0; mi < 4; ++mi)
#pragma unroll
      for (int ni = 0; ni < 4; ++ni)
        acc[mi][ni] = __builtin_amdgcn_mfma_f32_16x16x32_bf16(af[mi], bfr[ni], acc[mi][ni], 0, 0, 0);
    cur ^= 1;
  }

  if (MODE == 0) {
    const int t = n0 / CD;
#pragma unroll
    for (int mi = 0; mi < 4; ++mi) {
#pragma unroll
      for (int ni = 0; ni < 4; ++ni) {
        const int n = n0 + wn * 64 + ni * 16 + lr;
        const int rem = n - t * CD;
        const int h = rem >> 6, hd = rem & 63;
#pragma unroll
        for (int j = 0; j < 4; ++j) {
          const int m = m0 + wm * 64 + mi * 16 + lg * 4 + j;
          const int b = m >> 11, nn = m & 2047;
          const size_t oa = ((size_t)((b * NH + h) * SEQ + nn)) * HDM + hd;
          float val = acc[mi][ni][j];
          if (t == 0)
            Qo[oa] = (bf16)((val + qb[rem]) * QSCALE);
          else if (t == 1)
            Ko[oa] = (bf16)val;
          else
            Vo[oa] = (bf16)(val + vb[rem]);
        }
      }
    }
  } else {
#pragma unroll
    for (int mi = 0; mi < 4; ++mi)
#pragma unroll
      for (int ni = 0; ni < 4; ++ni) {
        const int n = n0 + wn * 64 + ni * 16 + lr;
#pragma unroll
        for (int j = 0; j < 4; ++j) {
          const int m = m0 + wm * 64 + mi * 16 + lg * 4 + j;
          Fo[(size_t)m * CD + n] = acc[mi][ni][j] + beff[n];
        }
      }
  }
}

// ---------------- V transpose: [BH][SEQ][64] -> [BH][64][SEQ] ----------------
__global__ void k_trv(const bf16* __restrict__ V, bf16* __restrict__ Vt) {
  __shared__ bf16 t[64][72];
  const int bh = blockIdx.y, s0 = blockIdx.x * 64;
  const int tid = threadIdx.x;
  const int row = tid >> 2, cc = (tid & 3) * 16;
  const bf16* src = V + ((size_t)bh * SEQ + s0 + row) * HDM + cc;
  bf16x8_t a = *(const bf16x8_t*)src;
  bf16x8_t b2 = *(const bf16x8_t*)(src + 8);
#pragma unroll
  for (int i = 0; i < 8; ++i) { t[row][cc + i] = a[i]; t[row][cc + 8 + i] = b2[i]; }
  __syncthreads();
  bf16x8_t o0, o1;
#pragma unroll
  for (int i = 0; i < 8; ++i) { o0[i] = t[cc + i][row]; o1[i] = t[cc + 8 + i][row]; }
  bf16* dst = Vt + ((size_t)bh * HDM + row) * SEQ + s0 + cc;
  *(bf16x8_t*)dst = o0;
  *(bf16x8_t*)(dst + 8) = o1;
}

// ---------------- flash attention ----------------
// 4 waves/block, 16 q-rows/wave, KVBLK=64.
// K,V block-shared in LDS, double-buffered, async16-staged with XOR 16B-chunk
// swizzle (linear LDS dest, inverse-swizzled GLOBAL src, swizzle on ds_read).
// TWO independent online-softmax chains per wave (k 0-31 / 32-63), merged at
// the end. QK/PV MFMA dataflow + P layout identical to the r5 passing kernel.
__global__ __launch_bounds__(256, 3) void k_attn(const bf16* __restrict__ Q,
                                                 const bf16* __restrict__ Kg,
                                                 const bf16* __restrict__ Vt,
                                                 bf16* __restrict__ Ao) {
  __shared__ bf16 Kl[2][64 * 64];
  __shared__ bf16 Vl[2][64 * 64];
  __shared__ bf16 P[4][16 * 72];
  const int tid = threadIdx.x;
  const int w = tid >> 6, lane = tid & 63;
  const int lq = lane & 15, lg = lane >> 4;
  const int bh = blockIdx.y;
  const int b = bh / NH, h = bh % NH;
  const int qrow0 = blockIdx.x * 64 + w * 16;

  const bf16* Qp = Q + ((size_t)bh * SEQ + qrow0) * HDM;
  const bf16* Kp = Kg + (size_t)bh * SEQ * HDM;
  const bf16* Vp = Vt + (size_t)bh * HDM * SEQ;

  // staging map: thread covers LDS row r=tid>>3, 16B chunk cs=tid&7 (+32 rows)
  const int sr = tid >> 3, scs = tid & 7;
  const int sr2 = sr + 32;
  bf16* kb0 = &Kl[0][w * 512]; bf16* kb1 = &Kl[1][w * 512];
  bf16* vb0 = &Vl[0][w * 512]; bf16* vb1 = &Vl[1][w * 512];

  auto stageKV = [&](int buf, int kb) {
    bf16* kd = buf ? kb1 : kb0;
    bf16* vd = buf ? vb1 : vb0;
    async16(Kp + (size_t)(kb + sr) * HDM + ((scs ^ (sr & 7)) * 8), kd);
    async16(Kp + (size_t)(kb + sr2) * HDM + ((scs ^ (sr2 & 7)) * 8), kd + 2048);
    async16(Vp + (size_t)sr * SEQ + kb + ((scs ^ (sr & 7)) * 8), vd);
    async16(Vp + (size_t)sr2 * SEQ + kb + ((scs ^ (sr2 & 7)) * 8), vd + 2048);
  };

  // Q fragments (hoisted): col q = lq, d = s*32 + lg*8 + jj
  bf16x8_t qf0 = *(const bf16x8_t*)(Qp + lq * HDM + lg * 8);
  bf16x8_t qf1 = *(const bf16x8_t*)(Qp + lq * HDM + 32 + lg * 8);

  f32x4_t oacc[2][4] = {};            // [chain][dt], O^T: d = dt*16+lg*4+j, q = lq
  float mrun[2] = {-1e30f, -1e30f};
  float lrun[2] = {0.f, 0.f};
  bf16* Pl = &P[w][0];
  const int sw = lq & 7;              // read-side swizzle key (row&7 == lq&7)

  stageKV(0, 0);
  int cur = 0;
  for (int kb = 0; kb < SEQ; kb += 64) {
    __syncthreads();                   // staged buf[cur] visible; joins prev iter
    if (kb + 64 < SEQ) stageKV(cur ^ 1, kb + 64);
    const bf16* Kc = &Kl[cur][0];
    const bf16* Vc = &Vl[cur][0];

    // QK^T swapped: st[c][nt] = S^T tile rows k = c*32+nt*16+lg*4+j, col q = lq
    f32x4_t st[2][2];
#pragma unroll
    for (int c = 0; c < 2; ++c)
#pragma unroll
      for (int nt = 0; nt < 2; ++nt) {
        const int row = c * 32 + nt * 16 + lq;
        bf16x8_t k0 = *(const bf16x8_t*)(Kc + row * 64 + ((lg ^ sw) * 8));
        bf16x8_t k1 = *(const bf16x8_t*)(Kc + row * 64 + (((4 + lg) ^ sw) * 8));
        f32x4_t z = {0.f, 0.f, 0.f, 0.f};
        z = __builtin_amdgcn_mfma_f32_16x16x32_bf16(k0, qf0, z, 0, 0, 0);
        st[c][nt] = __builtin_amdgcn_mfma_f32_16x16x32_bf16(k1, qf1, z, 0, 0, 0);
      }

    // two independent online-softmax chains (ILP)
    float corr[2];
#pragma unroll
    for (int c = 0; c < 2; ++c) {
      float m = st[c][0][0];
#pragma unroll
      for (int nt = 0; nt < 2; ++nt)
#pragma unroll
        for (int j = 0; j < 4; ++j) m = fmaxf(m, st[c][nt][j]);
      m = fmaxf(m, __shfl_xor(m, 16));
      m = fmaxf(m, __shfl_xor(m, 32));
      const float mnew = fmaxf(mrun[c], m);
      corr[c] = __expf(mrun[c] - mnew);
      mrun[c] = mnew;
      float sum = 0.f;
#pragma unroll
      for (int nt = 0; nt < 2; ++nt)
#pragma unroll
        for (int j = 0; j < 4; ++j) {
          float p = __expf(st[c][nt][j] - mnew);
          st[c][nt][j] = p;
          sum += p;
        }
      sum += __shfl_xor(sum, 16);
      sum += __shfl_xor(sum, 32);
      lrun[c] = lrun[c] * corr[c] + sum;
#pragma unroll
      for (int dt = 0; dt < 4; ++dt)
#pragma unroll
        for (int j = 0; j < 4; ++j) oacc[c][dt][j] *= corr[c];

      // stage P (8B writes): row q = lq, k = c*32 + nt*16 + lg*4 + {0..3}
#pragma unroll
      for (int nt = 0; nt < 2; ++nt) {
        u32x2_t pw = {pack_bf16(st[c][nt][0], st[c][nt][1]),
                      pack_bf16(st[c][nt][2], st[c][nt][3])};
        *(u32x2_t*)(Pl + lq * 72 + c * 32 + nt * 16 + lg * 4) = pw;
      }
    }

    // PV: chain c consumes k-half mt=c. A = V^T rows (d = dt*16+lq), B = P rows
#pragma unroll
    for (int c = 0; c < 2; ++c) {
      bf16x8_t pf = *(const bf16x8_t*)(Pl + lq * 72 + c * 32 + lg * 8);
#pragma unroll
      for (int dt = 0; dt < 4; ++dt) {
        const int vrow = dt * 16 + lq;
        bf16x8_t vf = *(const bf16x8_t*)(Vc + vrow * 64 + (((c * 4 + lg) ^ sw) * 8));
        oacc[c][dt] = __builtin_amdgcn_mfma_f32_16x16x32_bf16(vf, pf, oacc[c][dt], 0, 0, 0);
      }
    }
    cur ^= 1;
  }

  // merge the two chains, then write O rows (lane (lq,lg): q=lq, d=dt*16+lg*4+j)
  const float mm = fmaxf(mrun[0], mrun[1]);
  const float c0 = __expf(mrun[0] - mm), c1 = __expf(mrun[1] - mm);
  const float inv = 1.0f / (lrun[0] * c0 + lrun[1] * c1);
  bf16* dst = Ao + ((size_t)b * SEQ + qrow0 + lq) * CD + h * HDM;
#pragma unroll
  for (int dt = 0; dt < 4; ++dt) {
    bf16x4_t o4;
#pragma unroll
    for (int j = 0; j < 4; ++j)
      o4[j] = (bf16)((oacc[0][dt][j] * c0 + oacc[1][dt][j] * c1) * inv);
    *(bf16x4_t*)(dst + dt * 16 + lg * 4) = o4;
  }
}

// ---------------- launch ----------------
extern "C" void kernel_launch(void* const* d_in, const int* in_sizes, int n_in,
                              void* d_out, int out_size, void* d_ws, size_t ws_size,
                              hipStream_t stream) {
  const float* x    = (const float*)d_in[0];
  const float* qkvw = (const float*)d_in[1];
  const float* qb   = (const float*)d_in[2];
  const float* vb   = (const float*)d_in[3];
  const float* Aq   = (const float*)d_in[4];
  const float* Bq   = (const float*)d_in[5];
  const float* Wp   = (const float*)d_in[6];
  const float* bp   = (const float*)d_in[7];
  const float* Ap   = (const float*)d_in[8];
  const float* Bp   = (const float*)d_in[9];
  float* out = (float*)d_out;

  char* ws = (char*)d_ws;
  size_t off = 0;
  auto alloc = [&](size_t bytes) {
    void* p = ws + off;
    off += (bytes + 511) & ~size_t(511);
    return p;
  };
  const size_t M = (size_t)NB * SEQ;                 // 8192
  bf16* xb   = (bf16*)alloc(M * CD * 2);
  bf16* Wqe  = (bf16*)alloc((size_t)C3 * CD * 2);
  bf16* Wpe  = (bf16*)alloc((size_t)CD * CD * 2);
  float* T   = (float*)alloc(8 * CD * 4);
  float* be  = (float*)alloc(CD * 4);
  bf16* Qb   = (bf16*)alloc((size_t)BHN * SEQ * HDM * 2);
  bf16* Kb   = (bf16*)alloc((size_t)BHN * SEQ * HDM * 2);
  bf16* Vb   = (bf16*)alloc((size_t)BHN * SEQ * HDM * 2);
  bf16* Vtb  = (bf16*)alloc((size_t)BHN * SEQ * HDM * 2);
  bf16* attn = xb;  // xb dead after gemm<0>

  k_cast<<<2048, 256, 0, stream>>>(x, xb, (int)(M * CD / 4));
  k_prep_qkvw<<<(C3 * CD) / 256, 256, 0, stream>>>(qkvw, Aq, Bq, Wqe);
  k_prep_T<<<(8 * CD) / 256, 256, 0, stream>>>(Ap, Wp, T);
  k_prep_projw<<<(CD * CD) / 256, 256, 0, stream>>>(Wp, Bp, T, Wpe);
  k_prep_beff<<<3, 256, 0, stream>>>(bp, Ap, Bp, be);

  k_gemm<0><<<dim3(C3 / 128, M / 128), 256, 0, stream>>>(
      xb, Wqe, qb, vb, Qb, Kb, Vb, nullptr, nullptr);
  k_trv<<<dim3(SEQ / 64, BHN), 256, 0, stream>>>(Vb, Vtb);
  k_attn<<<dim3(SEQ / 64, BHN), 256, 0, stream>>>(Qb, Kb, Vtb, attn);
  k_gemm<1><<<dim3(CD / 128, M / 128), 256, 0, stream>>>(
      attn, Wpe, nullptr, nullptr, nullptr, nullptr, nullptr, be, out);
}

// Round 7
// 340.977 us; speedup vs baseline: 1.8797x; 1.0546x over previous
//
#include <hip/hip_runtime.h>
#include <cstdint>
#include <cstddef>

typedef __bf16 bf16;
typedef __bf16 bf16x4_t __attribute__((ext_vector_type(4)));
typedef __bf16 bf16x8_t __attribute__((ext_vector_type(8)));
typedef float f32x4_t __attribute__((ext_vector_type(4)));
typedef unsigned int u32;
typedef u32 u32x2_t __attribute__((ext_vector_type(2)));

#define DEV __device__ __forceinline__

static constexpr int CD  = 768;    // channels
static constexpr int C3  = 2304;   // 3*C
static constexpr int SEQ = 2048;
static constexpr int NB  = 4;      // batch
static constexpr int NH  = 12;     // heads
static constexpr int HDM = 64;     // head dim
static constexpr int BHN = NB * NH; // 48
// Q pre-scale: softmax scale 1/8 with log2(e) folded (scores in log2 domain)
static constexpr float QSCALE = 0.125f * 1.44269504088896340736f;
static constexpr float DEFER_THR = 4.0f;  // log2 domain; P bounded by 2^4

DEV void async16(const void* g, void* l) {
  __builtin_amdgcn_global_load_lds(
      (const __attribute__((address_space(1))) void*)g,
      (__attribute__((address_space(3))) void*)l, 16, 0, 0);
}

DEV int swz(int r) { return (r ^ (r >> 2)) & 3; }

// pack two fp32 -> one u32 of 2 bf16 via compiler (bf16) casts (RTNE)
DEV u32 pack_bf16(float lo, float hi) {
  unsigned short l = __builtin_bit_cast(unsigned short, (bf16)lo);
  unsigned short h = __builtin_bit_cast(unsigned short, (bf16)hi);
  return ((u32)h << 16) | (u32)l;
}

// ---------------- cast x fp32 -> bf16 ----------------
__global__ void k_cast(const float* __restrict__ x, bf16* __restrict__ o, int n4) {
  int i = blockIdx.x * blockDim.x + threadIdx.x;
  int stride = gridDim.x * blockDim.x;
  for (; i < n4; i += stride) {
    float4 v = reinterpret_cast<const float4*>(x)[i];
    bf16x4_t b;
    b[0] = (bf16)v.x; b[1] = (bf16)v.y; b[2] = (bf16)v.z; b[3] = (bf16)v.w;
    reinterpret_cast<bf16x4_t*>(o)[i] = b;
  }
}

// ---------------- weight folding (LoRA -> effective weights) ----------------
__global__ void k_prep_qkvw(const float* __restrict__ W, const float* __restrict__ Aq,
                            const float* __restrict__ Bq, bf16* __restrict__ We) {
  int idx = blockIdx.x * 256 + threadIdx.x;       // 2304*768
  int o = idx / CD, c = idx % CD;
  float s = 0.f;
#pragma unroll
  for (int r = 0; r < 8; ++r) s += Bq[o * 8 + r] * Aq[r * CD + c];
  We[idx] = (bf16)(W[idx] + 2.0f * s);
}

__global__ void k_prep_T(const float* __restrict__ Ap, const float* __restrict__ Wp,
                         float* __restrict__ T) {
  int idx = blockIdx.x * 256 + threadIdx.x;       // 8*768
  int r = idx / CD, cp = idx % CD;
  float s = 0.f;
  for (int c = 0; c < CD; ++c) s += Ap[r * CD + c] * Wp[(size_t)c * CD + cp];
  T[idx] = s;
}

__global__ void k_prep_projw(const float* __restrict__ Wp, const float* __restrict__ Bp,
                             const float* __restrict__ T, bf16* __restrict__ We) {
  int idx = blockIdx.x * 256 + threadIdx.x;       // 768*768
  int o = idx / CD, cp = idx % CD;
  float s = 0.f;
#pragma unroll
  for (int r = 0; r < 8; ++r) s += Bp[o * 8 + r] * T[r * CD + cp];
  We[idx] = (bf16)(Wp[idx] + 2.0f * s);
}

__global__ void k_prep_beff(const float* __restrict__ bp, const float* __restrict__ Ap,
                            const float* __restrict__ Bp, float* __restrict__ be) {
  int o = blockIdx.x * 256 + threadIdx.x;
  if (o >= CD) return;
  float s = 0.f;
  for (int r = 0; r < 8; ++r) {
    float t = 0.f;
    for (int c = 0; c < CD; ++c) t += Ap[r * CD + c] * bp[c];
    s += Bp[o * 8 + r] * t;
  }
  be[o] = bp[o] + 2.0f * s;
}

// ---------------- main GEMM: C[m][n] = sum_k A[m][k]*B[n][k] ----------------
// MFMA operands SWAPPED (A=W rows n, B=x rows m) so lane (lr,lg) holds
// m = tile_m+lr, n = tile_n + lg*4 + j -> 4 consecutive n per lane ->
// vectorized epilogue stores (16x 8B/16B instead of 64 scalar).
template <int MODE>
__global__ __launch_bounds__(256) void k_gemm(
    const bf16* __restrict__ Ag, const bf16* __restrict__ Bg,
    const float* __restrict__ qb, const float* __restrict__ vb,
    bf16* __restrict__ Qo, bf16* __restrict__ Ko, bf16* __restrict__ Vo,
    const float* __restrict__ beff, float* __restrict__ Fo) {
  __shared__ bf16 lds[2][2][128 * 32];
  const int tid = threadIdx.x;
  const int w = tid >> 6, lane = tid & 63;
  const int lr = lane & 15, lg = lane >> 4;
  const int m0 = blockIdx.y * 128, n0 = blockIdx.x * 128;
  const int wm = w >> 1, wn = w & 1;

  const int r0 = tid >> 2, gp0 = tid & 3;
  const int r1 = 64 + r0;
  const bf16* gA0 = Ag + (size_t)(m0 + r0) * CD + (gp0 ^ swz(r0)) * 8;
  const bf16* gA1 = Ag + (size_t)(m0 + r1) * CD + (gp0 ^ swz(r1)) * 8;
  const bf16* gB0 = Bg + (size_t)(n0 + r0) * CD + (gp0 ^ swz(r0)) * 8;
  const bf16* gB1 = Bg + (size_t)(n0 + r1) * CD + (gp0 ^ swz(r1)) * 8;
  const int dd0 = w * 1024, dd1 = 4096 + w * 1024;

  f32x4_t acc[4][4] = {};

  auto stage = [&](int buf, int kof) {
    char* ba = (char*)&lds[buf][0][0];
    char* bb = (char*)&lds[buf][1][0];
    async16(gA0 + kof, ba + dd0);
    async16(gA1 + kof, ba + dd1);
    async16(gB0 + kof, bb + dd0);
    async16(gB1 + kof, bb + dd1);
  };

  stage(0, 0);
  int cur = 0;
  const int NK = CD / 32;
  for (int kt = 0; kt < NK; ++kt) {
    __syncthreads();
    if (kt + 1 < NK) stage(cur ^ 1, (kt + 1) * 32);
    const char* ba = (const char*)&lds[cur][0][0];
    const char* bb = (const char*)&lds[cur][1][0];
    bf16x8_t af[4], bfr[4];
#pragma unroll
    for (int mi = 0; mi < 4; ++mi) {
      int rr = wm * 64 + mi * 16 + lr;
      af[mi] = *(const bf16x8_t*)(ba + rr * 64 + ((lg ^ swz(rr)) * 16));
    }
#pragma unroll
    for (int ni = 0; ni < 4; ++ni) {
      int rr = wn * 64 + ni * 16 + lr;
      bfr[ni] = *(const bf16x8_t*)(bb + rr * 64 + ((lg ^ swz(rr)) * 16));
    }
    // swapped: A = W rows (n), B = x rows (m) -> D[n_local][m_local]
#pragma unroll
    for (int mi = 0; mi < 4; ++mi)
#pragma unroll
      for (int ni = 0; ni < 4; ++ni)
        acc[mi][ni] = __builtin_amdgcn_mfma_f32_16x16x32_bf16(bfr[ni], af[mi], acc[mi][ni], 0, 0, 0);
    cur ^= 1;
  }

  if (MODE == 0) {
    const int t = n0 / CD;
#pragma unroll
    for (int mi = 0; mi < 4; ++mi) {
      const int m = m0 + wm * 64 + mi * 16 + lr;
      const int b = m >> 11, nn = m & 2047;
#pragma unroll
      for (int ni = 0; ni < 4; ++ni) {
        const int nb = n0 + wn * 64 + ni * 16 + lg * 4;
        const int rem = nb - t * CD;
        const int h = rem >> 6, hd = rem & 63;
        const size_t oa = ((size_t)((b * NH + h) * SEQ + nn)) * HDM + hd;
        bf16x4_t o4;
        if (t == 0) {
          const float4 bias = *(const float4*)(qb + rem);
          o4[0] = (bf16)((acc[mi][ni][0] + bias.x) * QSCALE);
          o4[1] = (bf16)((acc[mi][ni][1] + bias.y) * QSCALE);
          o4[2] = (bf16)((acc[mi][ni][2] + bias.z) * QSCALE);
          o4[3] = (bf16)((acc[mi][ni][3] + bias.w) * QSCALE);
          *(bf16x4_t*)(Qo + oa) = o4;
        } else if (t == 1) {
#pragma unroll
          for (int j = 0; j < 4; ++j) o4[j] = (bf16)acc[mi][ni][j];
          *(bf16x4_t*)(Ko + oa) = o4;
        } else {
          const float4 bias = *(const float4*)(vb + rem);
          o4[0] = (bf16)(acc[mi][ni][0] + bias.x);
          o4[1] = (bf16)(acc[mi][ni][1] + bias.y);
          o4[2] = (bf16)(acc[mi][ni][2] + bias.z);
          o4[3] = (bf16)(acc[mi][ni][3] + bias.w);
          *(bf16x4_t*)(Vo + oa) = o4;
        }
      }
    }
  } else {
#pragma unroll
    for (int mi = 0; mi < 4; ++mi) {
      const int m = m0 + wm * 64 + mi * 16 + lr;
#pragma unroll
      for (int ni = 0; ni < 4; ++ni) {
        const int nb = n0 + wn * 64 + ni * 16 + lg * 4;
        const float4 be4 = *(const float4*)(beff + nb);
        float4 o;
        o.x = acc[mi][ni][0] + be4.x;
        o.y = acc[mi][ni][1] + be4.y;
        o.z = acc[mi][ni][2] + be4.z;
        o.w = acc[mi][ni][3] + be4.w;
        *(float4*)(Fo + (size_t)m * CD + nb) = o;
      }
    }
  }
}

// ---------------- V transpose: [BH][SEQ][64] -> [BH][64][SEQ] ----------------
__global__ void k_trv(const bf16* __restrict__ V, bf16* __restrict__ Vt) {
  __shared__ bf16 t[64][72];
  const int bh = blockIdx.y, s0 = blockIdx.x * 64;
  const int tid = threadIdx.x;
  const int row = tid >> 2, cc = (tid & 3) * 16;
  const bf16* src = V + ((size_t)bh * SEQ + s0 + row) * HDM + cc;
  bf16x8_t a = *(const bf16x8_t*)src;
  bf16x8_t b2 = *(const bf16x8_t*)(src + 8);
#pragma unroll
  for (int i = 0; i < 8; ++i) { t[row][cc + i] = a[i]; t[row][cc + 8 + i] = b2[i]; }
  __syncthreads();
  bf16x8_t o0, o1;
#pragma unroll
  for (int i = 0; i < 8; ++i) { o0[i] = t[cc + i][row]; o1[i] = t[cc + 8 + i][row]; }
  bf16* dst = Vt + ((size_t)bh * HDM + row) * SEQ + s0 + cc;
  *(bf16x8_t*)dst = o0;
  *(bf16x8_t*)(dst + 8) = o1;
}

// ---------------- flash attention ----------------
// 4 waves/block, 16 q-rows/wave, KVBLK=64. K,V block-shared LDS, double-
// buffered async16 staging (XOR 16B-chunk swizzle, rule-21-compliant).
// Scores in log2 domain (Q pre-scaled by 0.125*log2e); exp2 throughout.
// T13 defer-rescale (THR=4): skip oacc rescale unless some row's max grew.
// lrun cross-lane reduce deferred to after the K-loop (per-lane partials).
__global__ __launch_bounds__(256, 3) void k_attn(const bf16* __restrict__ Q,
                                                 const bf16* __restrict__ Kg,
                                                 const bf16* __restrict__ Vt,
                                                 bf16* __restrict__ Ao) {
  __shared__ bf16 Kl[2][64 * 64];
  __shared__ bf16 Vl[2][64 * 64];
  __shared__ bf16 P[4][16 * 72];
  const int tid = threadIdx.x;
  const int w = tid >> 6, lane = tid & 63;
  const int lq = lane & 15, lg = lane >> 4;
  const int bh = blockIdx.y;
  const int b = bh / NH, h = bh % NH;
  const int qrow0 = blockIdx.x * 64 + w * 16;

  const bf16* Qp = Q + ((size_t)bh * SEQ + qrow0) * HDM;
  const bf16* Kp = Kg + (size_t)bh * SEQ * HDM;
  const bf16* Vp = Vt + (size_t)bh * HDM * SEQ;

  const int sr = tid >> 3, scs = tid & 7;
  const int sr2 = sr + 32;
  bf16* kb0 = &Kl[0][w * 512]; bf16* kb1 = &Kl[1][w * 512];
  bf16* vb0 = &Vl[0][w * 512]; bf16* vb1 = &Vl[1][w * 512];

  auto stageKV = [&](int buf, int kb) {
    bf16* kd = buf ? kb1 : kb0;
    bf16* vd = buf ? vb1 : vb0;
    async16(Kp + (size_t)(kb + sr) * HDM + ((scs ^ (sr & 7)) * 8), kd);
    async16(Kp + (size_t)(kb + sr2) * HDM + ((scs ^ (sr2 & 7)) * 8), kd + 2048);
    async16(Vp + (size_t)sr * SEQ + kb + ((scs ^ (sr & 7)) * 8), vd);
    async16(Vp + (size_t)sr2 * SEQ + kb + ((scs ^ (sr2 & 7)) * 8), vd + 2048);
  };

  bf16x8_t qf0 = *(const bf16x8_t*)(Qp + lq * HDM + lg * 8);
  bf16x8_t qf1 = *(const bf16x8_t*)(Qp + lq * HDM + 32 + lg * 8);

  f32x4_t oacc[2][4] = {};            // [chain][dt], O^T: d = dt*16+lg*4+j, q = lq
  float mrun[2] = {-1e30f, -1e30f};
  float lsum[2] = {0.f, 0.f};         // per-lane partial denominators
  bf16* Pl = &P[w][0];
  const int sw = lq & 7;

  stageKV(0, 0);
  int cur = 0;
  for (int kb = 0; kb < SEQ; kb += 64) {
    __syncthreads();
    if (kb + 64 < SEQ) stageKV(cur ^ 1, kb + 64);
    const bf16* Kc = &Kl[cur][0];
    const bf16* Vc = &Vl[cur][0];

    f32x4_t st[2][2];
#pragma unroll
    for (int c = 0; c < 2; ++c)
#pragma unroll
      for (int nt = 0; nt < 2; ++nt) {
        const int row = c * 32 + nt * 16 + lq;
        bf16x8_t k0 = *(const bf16x8_t*)(Kc + row * 64 + ((lg ^ sw) * 8));
        bf16x8_t k1 = *(const bf16x8_t*)(Kc + row * 64 + (((4 + lg) ^ sw) * 8));
        f32x4_t z = {0.f, 0.f, 0.f, 0.f};
        z = __builtin_amdgcn_mfma_f32_16x16x32_bf16(k0, qf0, z, 0, 0, 0);
        st[c][nt] = __builtin_amdgcn_mfma_f32_16x16x32_bf16(k1, qf1, z, 0, 0, 0);
      }

#pragma unroll
    for (int c = 0; c < 2; ++c) {
      float m = st[c][0][0];
#pragma unroll
      for (int nt = 0; nt < 2; ++nt)
#pragma unroll
        for (int j = 0; j < 4; ++j) m = fmaxf(m, st[c][nt][j]);
      m = fmaxf(m, __shfl_xor(m, 16));
      m = fmaxf(m, __shfl_xor(m, 32));
      // T13 defer: rescale only if some q-row's max grew past THR
      if (__any(m > mrun[c] + DEFER_THR)) {
        const float mnew = fmaxf(mrun[c], m);
        const float corr = __builtin_amdgcn_exp2f(mrun[c] - mnew);
        mrun[c] = mnew;
        lsum[c] *= corr;
#pragma unroll
        for (int dt = 0; dt < 4; ++dt)
#pragma unroll
          for (int j = 0; j < 4; ++j) oacc[c][dt][j] *= corr;
      }
      float sum = 0.f;
#pragma unroll
      for (int nt = 0; nt < 2; ++nt)
#pragma unroll
        for (int j = 0; j < 4; ++j) {
          float p = __builtin_amdgcn_exp2f(st[c][nt][j] - mrun[c]);
          st[c][nt][j] = p;
          sum += p;
        }
      lsum[c] += sum;                 // cross-lane reduce deferred to epilogue

#pragma unroll
      for (int nt = 0; nt < 2; ++nt) {
        u32x2_t pw = {pack_bf16(st[c][nt][0], st[c][nt][1]),
                      pack_bf16(st[c][nt][2], st[c][nt][3])};
        *(u32x2_t*)(Pl + lq * 72 + c * 32 + nt * 16 + lg * 4) = pw;
      }
    }

#pragma unroll
    for (int c = 0; c < 2; ++c) {
      bf16x8_t pf = *(const bf16x8_t*)(Pl + lq * 72 + c * 32 + lg * 8);
#pragma unroll
      for (int dt = 0; dt < 4; ++dt) {
        const int vrow = dt * 16 + lq;
        bf16x8_t vf = *(const bf16x8_t*)(Vc + vrow * 64 + (((c * 4 + lg) ^ sw) * 8));
        oacc[c][dt] = __builtin_amdgcn_mfma_f32_16x16x32_bf16(vf, pf, oacc[c][dt], 0, 0, 0);
      }
    }
    cur ^= 1;
  }

  // reduce deferred denominators, merge chains, write O rows
  float l0 = lsum[0], l1 = lsum[1];
  l0 += __shfl_xor(l0, 16); l0 += __shfl_xor(l0, 32);
  l1 += __shfl_xor(l1, 16); l1 += __shfl_xor(l1, 32);
  const float mm = fmaxf(mrun[0], mrun[1]);
  const float c0 = __builtin_amdgcn_exp2f(mrun[0] - mm);
  const float c1 = __builtin_amdgcn_exp2f(mrun[1] - mm);
  const float inv = 1.0f / (l0 * c0 + l1 * c1);
  bf16* dst = Ao + ((size_t)b * SEQ + qrow0 + lq) * CD + h * HDM;
#pragma unroll
  for (int dt = 0; dt < 4; ++dt) {
    bf16x4_t o4;
#pragma unroll
    for (int j = 0; j < 4; ++j)
      o4[j] = (bf16)((oacc[0][dt][j] * c0 + oacc[1][dt][j] * c1) * inv);
    *(bf16x4_t*)(dst + dt * 16 + lg * 4) = o4;
  }
}

// ---------------- launch ----------------
extern "C" void kernel_launch(void* const* d_in, const int* in_sizes, int n_in,
                              void* d_out, int out_size, void* d_ws, size_t ws_size,
                              hipStream_t stream) {
  const float* x    = (const float*)d_in[0];
  const float* qkvw = (const float*)d_in[1];
  const float* qb   = (const float*)d_in[2];
  const float* vb   = (const float*)d_in[3];
  const float* Aq   = (const float*)d_in[4];
  const float* Bq   = (const float*)d_in[5];
  const float* Wp   = (const float*)d_in[6];
  const float* bp   = (const float*)d_in[7];
  const float* Ap   = (const float*)d_in[8];
  const float* Bp   = (const float*)d_in[9];
  float* out = (float*)d_out;

  char* ws = (char*)d_ws;
  size_t off = 0;
  auto alloc = [&](size_t bytes) {
    void* p = ws + off;
    off += (bytes + 511) & ~size_t(511);
    return p;
  };
  const size_t M = (size_t)NB * SEQ;                 // 8192
  bf16* xb   = (bf16*)alloc(M * CD * 2);
  bf16* Wqe  = (bf16*)alloc((size_t)C3 * CD * 2);
  bf16* Wpe  = (bf16*)alloc((size_t)CD * CD * 2);
  float* T   = (float*)alloc(8 * CD * 4);
  float* be  = (float*)alloc(CD * 4);
  bf16* Qb   = (bf16*)alloc((size_t)BHN * SEQ * HDM * 2);
  bf16* Kb   = (bf16*)alloc((size_t)BHN * SEQ * HDM * 2);
  bf16* Vb   = (bf16*)alloc((size_t)BHN * SEQ * HDM * 2);
  bf16* Vtb  = (bf16*)alloc((size_t)BHN * SEQ * HDM * 2);
  bf16* attn = xb;  // xb dead after gemm<0>

  k_cast<<<2048, 256, 0, stream>>>(x, xb, (int)(M * CD / 4));
  k_prep_qkvw<<<(C3 * CD) / 256, 256, 0, stream>>>(qkvw, Aq, Bq, Wqe);
  k_prep_T<<<(8 * CD) / 256, 256, 0, stream>>>(Ap, Wp, T);
  k_prep_projw<<<(CD * CD) / 256, 256, 0, stream>>>(Wp, Bp, T, Wpe);
  k_prep_beff<<<3, 256, 0, stream>>>(bp, Ap, Bp, be);

  k_gemm<0><<<dim3(C3 / 128, M / 128), 256, 0, stream>>>(
      xb, Wqe, qb, vb, Qb, Kb, Vb, nullptr, nullptr);
  k_trv<<<dim3(SEQ / 64, BHN), 256, 0, stream>>>(Vb, Vtb);
  k_attn<<<dim3(SEQ / 64, BHN), 256, 0, stream>>>(Qb, Kb, Vtb, attn);
  k_gemm<1><<<dim3(CD / 128, M / 128), 256, 0, stream>>>(
      attn, Wpe, nullptr, nullptr, nullptr, nullptr, nullptr, be, out);
}

// Round 8
// 238.311 us; speedup vs baseline: 2.6895x; 1.4308x over previous
//
#include <hip/hip_runtime.h>
#include <cstdint>
#include <cstddef>

typedef __bf16 bf16;
typedef __bf16 bf16x4_t __attribute__((ext_vector_type(4)));
typedef __bf16 bf16x8_t __attribute__((ext_vector_type(8)));
typedef float f32x4_t __attribute__((ext_vector_type(4)));
typedef unsigned int u32;
typedef u32 u32x2_t __attribute__((ext_vector_type(2)));

#define DEV __device__ __forceinline__

static constexpr int CD  = 768;    // channels
static constexpr int C3  = 2304;   // 3*C
static constexpr int SEQ = 2048;
static constexpr int NB  = 4;      // batch
static constexpr int NH  = 12;     // heads
static constexpr int HDM = 64;     // head dim
static constexpr int BHN = NB * NH; // 48
// Q pre-scale: softmax scale 1/8 with log2(e) folded (scores in log2 domain)
static constexpr float QSCALE = 0.125f * 1.44269504088896340736f;
static constexpr float DEFER_THR = 4.0f;  // log2 domain; P bounded by 2^4

DEV void async16(const void* g, void* l) {
  __builtin_amdgcn_global_load_lds(
      (const __attribute__((address_space(1))) void*)g,
      (__attribute__((address_space(3))) void*)l, 16, 0, 0);
}

DEV int swz(int r) { return (r ^ (r >> 2)) & 3; }

// pack two fp32 -> one u32 of 2 bf16 via compiler (bf16) casts (RTNE)
DEV u32 pack_bf16(float lo, float hi) {
  unsigned short l = __builtin_bit_cast(unsigned short, (bf16)lo);
  unsigned short h = __builtin_bit_cast(unsigned short, (bf16)hi);
  return ((u32)h << 16) | (u32)l;
}

// ---------------- cast x fp32 -> bf16 ----------------
__global__ void k_cast(const float* __restrict__ x, bf16* __restrict__ o, int n4) {
  int i = blockIdx.x * blockDim.x + threadIdx.x;
  int stride = gridDim.x * blockDim.x;
  for (; i < n4; i += stride) {
    float4 v = reinterpret_cast<const float4*>(x)[i];
    bf16x4_t b;
    b[0] = (bf16)v.x; b[1] = (bf16)v.y; b[2] = (bf16)v.z; b[3] = (bf16)v.w;
    reinterpret_cast<bf16x4_t*>(o)[i] = b;
  }
}

// ---------------- weight folding (LoRA -> effective weights) ----------------
__global__ void k_prep_qkvw(const float* __restrict__ W, const float* __restrict__ Aq,
                            const float* __restrict__ Bq, bf16* __restrict__ We) {
  int idx = blockIdx.x * 256 + threadIdx.x;       // 2304*768
  int o = idx / CD, c = idx % CD;
  float s = 0.f;
#pragma unroll
  for (int r = 0; r < 8; ++r) s += Bq[o * 8 + r] * Aq[r * CD + c];
  We[idx] = (bf16)(W[idx] + 2.0f * s);
}

__global__ void k_prep_T(const float* __restrict__ Ap, const float* __restrict__ Wp,
                         float* __restrict__ T) {
  int idx = blockIdx.x * 256 + threadIdx.x;       // 8*768
  int r = idx / CD, cp = idx % CD;
  float s = 0.f;
  for (int c = 0; c < CD; ++c) s += Ap[r * CD + c] * Wp[(size_t)c * CD + cp];
  T[idx] = s;
}

__global__ void k_prep_projw(const float* __restrict__ Wp, const float* __restrict__ Bp,
                             const float* __restrict__ T, bf16* __restrict__ We) {
  int idx = blockIdx.x * 256 + threadIdx.x;       // 768*768
  int o = idx / CD, cp = idx % CD;
  float s = 0.f;
#pragma unroll
  for (int r = 0; r < 8; ++r) s += Bp[o * 8 + r] * T[r * CD + cp];
  We[idx] = (bf16)(Wp[idx] + 2.0f * s);
}

// b_eff[o] = bp[o] + 2 * sum_r Bp[o][r] * (sum_c Ap[r][c] * bp[c])
// ONE block, 256 threads. Phase 1: r = tid>>5 (8 groups of 32 lanes), strided
// partial sums + 5-step shfl_xor reduce (stays within each 32-lane half-wave).
// Phase 2: each thread emits 3 outputs from the LDS-cached t[8].
__global__ void k_prep_beff(const float* __restrict__ bp, const float* __restrict__ Ap,
                            const float* __restrict__ Bp, float* __restrict__ be) {
  __shared__ float tl[8];
  const int tid = threadIdx.x;
  const int r = tid >> 5, cl = tid & 31;
  float part = 0.f;
  for (int c = cl; c < CD; c += 32) part += Ap[r * CD + c] * bp[c];
#pragma unroll
  for (int d = 1; d < 32; d <<= 1) part += __shfl_xor(part, d);
  if (cl == 0) tl[r] = part;
  __syncthreads();
  for (int o = tid; o < CD; o += 256) {
    float s = 0.f;
#pragma unroll
    for (int rr = 0; rr < 8; ++rr) s += Bp[o * 8 + rr] * tl[rr];
    be[o] = bp[o] + 2.0f * s;
  }
}

// ---------------- main GEMM: C[m][n] = sum_k A[m][k]*B[n][k] ----------------
// MFMA operands SWAPPED (A=W rows n, B=x rows m) so lane (lr,lg) holds
// m = tile_m+lr, n = tile_n + lg*4 + j -> 4 consecutive n per lane ->
// vectorized epilogue stores (16x 8B/16B instead of 64 scalar).
template <int MODE>
__global__ __launch_bounds__(256) void k_gemm(
    const bf16* __restrict__ Ag, const bf16* __restrict__ Bg,
    const float* __restrict__ qb, const float* __restrict__ vb,
    bf16* __restrict__ Qo, bf16* __restrict__ Ko, bf16* __restrict__ Vo,
    const float* __restrict__ beff, float* __restrict__ Fo) {
  __shared__ bf16 lds[2][2][128 * 32];
  const int tid = threadIdx.x;
  const int w = tid >> 6, lane = tid & 63;
  const int lr = lane & 15, lg = lane >> 4;
  const int m0 = blockIdx.y * 128, n0 = blockIdx.x * 128;
  const int wm = w >> 1, wn = w & 1;

  const int r0 = tid >> 2, gp0 = tid & 3;
  const int r1 = 64 + r0;
  const bf16* gA0 = Ag + (size_t)(m0 + r0) * CD + (gp0 ^ swz(r0)) * 8;
  const bf16* gA1 = Ag + (size_t)(m0 + r1) * CD + (gp0 ^ swz(r1)) * 8;
  const bf16* gB0 = Bg + (size_t)(n0 + r0) * CD + (gp0 ^ swz(r0)) * 8;
  const bf16* gB1 = Bg + (size_t)(n0 + r1) * CD + (gp0 ^ swz(r1)) * 8;
  const int dd0 = w * 1024, dd1 = 4096 + w * 1024;

  f32x4_t acc[4][4] = {};

  auto stage = [&](int buf, int kof) {
    char* ba = (char*)&lds[buf][0][0];
    char* bb = (char*)&lds[buf][1][0];
    async16(gA0 + kof, ba + dd0);
    async16(gA1 + kof, ba + dd1);
    async16(gB0 + kof, bb + dd0);
    async16(gB1 + kof, bb + dd1);
  };

  stage(0, 0);
  int cur = 0;
  const int NK = CD / 32;
  for (int kt = 0; kt < NK; ++kt) {
    __syncthreads();
    if (kt + 1 < NK) stage(cur ^ 1, (kt + 1) * 32);
    const char* ba = (const char*)&lds[cur][0][0];
    const char* bb = (const char*)&lds[cur][1][0];
    bf16x8_t af[4], bfr[4];
#pragma unroll
    for (int mi = 0; mi < 4; ++mi) {
      int rr = wm * 64 + mi * 16 + lr;
      af[mi] = *(const bf16x8_t*)(ba + rr * 64 + ((lg ^ swz(rr)) * 16));
    }
#pragma unroll
    for (int ni = 0; ni < 4; ++ni) {
      int rr = wn * 64 + ni * 16 + lr;
      bfr[ni] = *(const bf16x8_t*)(bb + rr * 64 + ((lg ^ swz(rr)) * 16));
    }
    // swapped: A = W rows (n), B = x rows (m) -> D[n_local][m_local]
#pragma unroll
    for (int mi = 0; mi < 4; ++mi)
#pragma unroll
      for (int ni = 0; ni < 4; ++ni)
        acc[mi][ni] = __builtin_amdgcn_mfma_f32_16x16x32_bf16(bfr[ni], af[mi], acc[mi][ni], 0, 0, 0);
    cur ^= 1;
  }

  if (MODE == 0) {
    const int t = n0 / CD;
#pragma unroll
    for (int mi = 0; mi < 4; ++mi) {
      const int m = m0 + wm * 64 + mi * 16 + lr;
      const int b = m >> 11, nn = m & 2047;
#pragma unroll
      for (int ni = 0; ni < 4; ++ni) {
        const int nb = n0 + wn * 64 + ni * 16 + lg * 4;
        const int rem = nb - t * CD;
        const int h = rem >> 6, hd = rem & 63;
        const size_t oa = ((size_t)((b * NH + h) * SEQ + nn)) * HDM + hd;
        bf16x4_t o4;
        if (t == 0) {
          const float4 bias = *(const float4*)(qb + rem);
          o4[0] = (bf16)((acc[mi][ni][0] + bias.x) * QSCALE);
          o4[1] = (bf16)((acc[mi][ni][1] + bias.y) * QSCALE);
          o4[2] = (bf16)((acc[mi][ni][2] + bias.z) * QSCALE);
          o4[3] = (bf16)((acc[mi][ni][3] + bias.w) * QSCALE);
          *(bf16x4_t*)(Qo + oa) = o4;
        } else if (t == 1) {
#pragma unroll
          for (int j = 0; j < 4; ++j) o4[j] = (bf16)acc[mi][ni][j];
          *(bf16x4_t*)(Ko + oa) = o4;
        } else {
          const float4 bias = *(const float4*)(vb + rem);
          o4[0] = (bf16)(acc[mi][ni][0] + bias.x);
          o4[1] = (bf16)(acc[mi][ni][1] + bias.y);
          o4[2] = (bf16)(acc[mi][ni][2] + bias.z);
          o4[3] = (bf16)(acc[mi][ni][3] + bias.w);
          *(bf16x4_t*)(Vo + oa) = o4;
        }
      }
    }
  } else {
#pragma unroll
    for (int mi = 0; mi < 4; ++mi) {
      const int m = m0 + wm * 64 + mi * 16 + lr;
#pragma unroll
      for (int ni = 0; ni < 4; ++ni) {
        const int nb = n0 + wn * 64 + ni * 16 + lg * 4;
        const float4 be4 = *(const float4*)(beff + nb);
        float4 o;
        o.x = acc[mi][ni][0] + be4.x;
        o.y = acc[mi][ni][1] + be4.y;
        o.z = acc[mi][ni][2] + be4.z;
        o.w = acc[mi][ni][3] + be4.w;
        *(float4*)(Fo + (size_t)m * CD + nb) = o;
      }
    }
  }
}

// ---------------- V transpose: [BH][SEQ][64] -> [BH][64][SEQ] ----------------
__global__ void k_trv(const bf16* __restrict__ V, bf16* __restrict__ Vt) {
  __shared__ bf16 t[64][72];
  const int bh = blockIdx.y, s0 = blockIdx.x * 64;
  const int tid = threadIdx.x;
  const int row = tid >> 2, cc = (tid & 3) * 16;
  const bf16* src = V + ((size_t)bh * SEQ + s0 + row) * HDM + cc;
  bf16x8_t a = *(const bf16x8_t*)src;
  bf16x8_t b2 = *(const bf16x8_t*)(src + 8);
#pragma unroll
  for (int i = 0; i < 8; ++i) { t[row][cc + i] = a[i]; t[row][cc + 8 + i] = b2[i]; }
  __syncthreads();
  bf16x8_t o0, o1;
#pragma unroll
  for (int i = 0; i < 8; ++i) { o0[i] = t[cc + i][row]; o1[i] = t[cc + 8 + i][row]; }
  bf16* dst = Vt + ((size_t)bh * HDM + row) * SEQ + s0 + cc;
  *(bf16x8_t*)dst = o0;
  *(bf16x8_t*)(dst + 8) = o1;
}

// ---------------- flash attention ----------------
// 4 waves/block, 16 q-rows/wave, KVBLK=64. K,V block-shared LDS, double-
// buffered async16 staging (XOR 16B-chunk swizzle, rule-21-compliant).
// Scores in log2 domain (Q pre-scaled by 0.125*log2e); exp2 throughout.
// T13 defer-rescale (THR=4): skip oacc rescale unless some row's max grew.
// lrun cross-lane reduce deferred to after the K-loop (per-lane partials).
__global__ __launch_bounds__(256, 3) void k_attn(const bf16* __restrict__ Q,
                                                 const bf16* __restrict__ Kg,
                                                 const bf16* __restrict__ Vt,
                                                 bf16* __restrict__ Ao) {
  __shared__ bf16 Kl[2][64 * 64];
  __shared__ bf16 Vl[2][64 * 64];
  __shared__ bf16 P[4][16 * 72];
  const int tid = threadIdx.x;
  const int w = tid >> 6, lane = tid & 63;
  const int lq = lane & 15, lg = lane >> 4;
  const int bh = blockIdx.y;
  const int b = bh / NH, h = bh % NH;
  const int qrow0 = blockIdx.x * 64 + w * 16;

  const bf16* Qp = Q + ((size_t)bh * SEQ + qrow0) * HDM;
  const bf16* Kp = Kg + (size_t)bh * SEQ * HDM;
  const bf16* Vp = Vt + (size_t)bh * HDM * SEQ;

  const int sr = tid >> 3, scs = tid & 7;
  const int sr2 = sr + 32;
  bf16* kb0 = &Kl[0][w * 512]; bf16* kb1 = &Kl[1][w * 512];
  bf16* vb0 = &Vl[0][w * 512]; bf16* vb1 = &Vl[1][w * 512];

  auto stageKV = [&](int buf, int kb) {
    bf16* kd = buf ? kb1 : kb0;
    bf16* vd = buf ? vb1 : vb0;
    async16(Kp + (size_t)(kb + sr) * HDM + ((scs ^ (sr & 7)) * 8), kd);
    async16(Kp + (size_t)(kb + sr2) * HDM + ((scs ^ (sr2 & 7)) * 8), kd + 2048);
    async16(Vp + (size_t)sr * SEQ + kb + ((scs ^ (sr & 7)) * 8), vd);
    async16(Vp + (size_t)sr2 * SEQ + kb + ((scs ^ (sr2 & 7)) * 8), vd + 2048);
  };

  bf16x8_t qf0 = *(const bf16x8_t*)(Qp + lq * HDM + lg * 8);
  bf16x8_t qf1 = *(const bf16x8_t*)(Qp + lq * HDM + 32 + lg * 8);

  f32x4_t oacc[2][4] = {};            // [chain][dt], O^T: d = dt*16+lg*4+j, q = lq
  float mrun[2] = {-1e30f, -1e30f};
  float lsum[2] = {0.f, 0.f};         // per-lane partial denominators
  bf16* Pl = &P[w][0];
  const int sw = lq & 7;

  stageKV(0, 0);
  int cur = 0;
  for (int kb = 0; kb < SEQ; kb += 64) {
    __syncthreads();
    if (kb + 64 < SEQ) stageKV(cur ^ 1, kb + 64);
    const bf16* Kc = &Kl[cur][0];
    const bf16* Vc = &Vl[cur][0];

    f32x4_t st[2][2];
#pragma unroll
    for (int c = 0; c < 2; ++c)
#pragma unroll
      for (int nt = 0; nt < 2; ++nt) {
        const int row = c * 32 + nt * 16 + lq;
        bf16x8_t k0 = *(const bf16x8_t*)(Kc + row * 64 + ((lg ^ sw) * 8));
        bf16x8_t k1 = *(const bf16x8_t*)(Kc + row * 64 + (((4 + lg) ^ sw) * 8));
        f32x4_t z = {0.f, 0.f, 0.f, 0.f};
        z = __builtin_amdgcn_mfma_f32_16x16x32_bf16(k0, qf0, z, 0, 0, 0);
        st[c][nt] = __builtin_amdgcn_mfma_f32_16x16x32_bf16(k1, qf1, z, 0, 0, 0);
      }

#pragma unroll
    for (int c = 0; c < 2; ++c) {
      float m = st[c][0][0];
#pragma unroll
      for (int nt = 0; nt < 2; ++nt)
#pragma unroll
        for (int j = 0; j < 4; ++j) m = fmaxf(m, st[c][nt][j]);
      m = fmaxf(m, __shfl_xor(m, 16));
      m = fmaxf(m, __shfl_xor(m, 32));
      // T13 defer: rescale only if some q-row's max grew past THR
      if (__any(m > mrun[c] + DEFER_THR)) {
        const float mnew = fmaxf(mrun[c], m);
        const float corr = __builtin_amdgcn_exp2f(mrun[c] - mnew);
        mrun[c] = mnew;
        lsum[c] *= corr;
#pragma unroll
        for (int dt = 0; dt < 4; ++dt)
#pragma unroll
          for (int j = 0; j < 4; ++j) oacc[c][dt][j] *= corr;
      }
      float sum = 0.f;
#pragma unroll
      for (int nt = 0; nt < 2; ++nt)
#pragma unroll
        for (int j = 0; j < 4; ++j) {
          float p = __builtin_amdgcn_exp2f(st[c][nt][j] - mrun[c]);
          st[c][nt][j] = p;
          sum += p;
        }
      lsum[c] += sum;                 // cross-lane reduce deferred to epilogue

#pragma unroll
      for (int nt = 0; nt < 2; ++nt) {
        u32x2_t pw = {pack_bf16(st[c][nt][0], st[c][nt][1]),
                      pack_bf16(st[c][nt][2], st[c][nt][3])};
        *(u32x2_t*)(Pl + lq * 72 + c * 32 + nt * 16 + lg * 4) = pw;
      }
    }

#pragma unroll
    for (int c = 0; c < 2; ++c) {
      bf16x8_t pf = *(const bf16x8_t*)(Pl + lq * 72 + c * 32 + lg * 8);
#pragma unroll
      for (int dt = 0; dt < 4; ++dt) {
        const int vrow = dt * 16 + lq;
        bf16x8_t vf = *(const bf16x8_t*)(Vc + vrow * 64 + (((c * 4 + lg) ^ sw) * 8));
        oacc[c][dt] = __builtin_amdgcn_mfma_f32_16x16x32_bf16(vf, pf, oacc[c][dt], 0, 0, 0);
      }
    }
    cur ^= 1;
  }

  // reduce deferred denominators, merge chains, write O rows
  float l0 = lsum[0], l1 = lsum[1];
  l0 += __shfl_xor(l0, 16); l0 += __shfl_xor(l0, 32);
  l1 += __shfl_xor(l1, 16); l1 += __shfl_xor(l1, 32);
  const float mm = fmaxf(mrun[0], mrun[1]);
  const float c0 = __builtin_amdgcn_exp2f(mrun[0] - mm);
  const float c1 = __builtin_amdgcn_exp2f(mrun[1] - mm);
  const float inv = 1.0f / (l0 * c0 + l1 * c1);
  bf16* dst = Ao + ((size_t)b * SEQ + qrow0 + lq) * CD + h * HDM;
#pragma unroll
  for (int dt = 0; dt < 4; ++dt) {
    bf16x4_t o4;
#pragma unroll
    for (int j = 0; j < 4; ++j)
      o4[j] = (bf16)((oacc[0][dt][j] * c0 + oacc[1][dt][j] * c1) * inv);
    *(bf16x4_t*)(dst + dt * 16 + lg * 4) = o4;
  }
}

// ---------------- launch ----------------
extern "C" void kernel_launch(void* const* d_in, const int* in_sizes, int n_in,
                              void* d_out, int out_size, void* d_ws, size_t ws_size,
                              hipStream_t stream) {
  const float* x    = (const float*)d_in[0];
  const float* qkvw = (const float*)d_in[1];
  const float* qb   = (const float*)d_in[2];
  const float* vb   = (const float*)d_in[3];
  const float* Aq   = (const float*)d_in[4];
  const float* Bq   = (const float*)d_in[5];
  const float* Wp   = (const float*)d_in[6];
  const float* bp   = (const float*)d_in[7];
  const float* Ap   = (const float*)d_in[8];
  const float* Bp   = (const float*)d_in[9];
  float* out = (float*)d_out;

  char* ws = (char*)d_ws;
  size_t off = 0;
  auto alloc = [&](size_t bytes) {
    void* p = ws + off;
    off += (bytes + 511) & ~size_t(511);
    return p;
  };
  const size_t M = (size_t)NB * SEQ;                 // 8192
  bf16* xb   = (bf16*)alloc(M * CD * 2);
  bf16* Wqe  = (bf16*)alloc((size_t)C3 * CD * 2);
  bf16* Wpe  = (bf16*)alloc((size_t)CD * CD * 2);
  float* T   = (float*)alloc(8 * CD * 4);
  float* be  = (float*)alloc(CD * 4);
  bf16* Qb   = (bf16*)alloc((size_t)BHN * SEQ * HDM * 2);
  bf16* Kb   = (bf16*)alloc((size_t)BHN * SEQ * HDM * 2);
  bf16* Vb   = (bf16*)alloc((size_t)BHN * SEQ * HDM * 2);
  bf16* Vtb  = (bf16*)alloc((size_t)BHN * SEQ * HDM * 2);
  bf16* attn = xb;  // xb dead after gemm<0>

  k_cast<<<2048, 256, 0, stream>>>(x, xb, (int)(M * CD / 4));
  k_prep_qkvw<<<(C3 * CD) / 256, 256, 0, stream>>>(qkvw, Aq, Bq, Wqe);
  k_prep_T<<<(8 * CD) / 256, 256, 0, stream>>>(Ap, Wp, T);
  k_prep_projw<<<(CD * CD) / 256, 256, 0, stream>>>(Wp, Bp, T, Wpe);
  k_prep_beff<<<1, 256, 0, stream>>>(bp, Ap, Bp, be);

  k_gemm<0><<<dim3(C3 / 128, M / 128), 256, 0, stream>>>(
      xb, Wqe, qb, vb, Qb, Kb, Vb, nullptr, nullptr);
  k_trv<<<dim3(SEQ / 64, BHN), 256, 0, stream>>>(Vb, Vtb);
  k_attn<<<dim3(SEQ / 64, BHN), 256, 0, stream>>>(Qb, Kb, Vtb, attn);
  k_gemm<1><<<dim3(CD / 128, M / 128), 256, 0, stream>>>(
      attn, Wpe, nullptr, nullptr, nullptr, nullptr, nullptr, be, out);
}